// Round 3
// baseline (1346.931 us; speedup 1.0000x reference)
//
#include <hip/hip_runtime.h>
#include <cstdint>

#define N_NODES 20000
#define N_EDGES 100000
#define LEAKK 0.1f
#define BN_EPS 1e-5f

__device__ __forceinline__ float lrelu(float v) { return v > 0.f ? v : LEAKK * v; }
__device__ __forceinline__ float4 ld4(const float* p) { return *reinterpret_cast<const float4*>(p); }

__device__ __forceinline__ void atomAddF(float* p, float v) {
#if defined(__HIP_DEVICE_COMPILE__)
    unsafeAtomicAdd(p, v);   // hardware global_atomic_add_f32
#else
    atomicAdd(p, v);
#endif
}

// ---------------- column stats: sum + sumsq over rows ----------------
template<int C>
__global__ void stats_kernel(const float* __restrict__ v, int rows, float* __restrict__ out /*[2C]*/) {
    float s[C], q[C];
    #pragma unroll
    for (int c = 0; c < C; ++c) { s[c] = 0.f; q[c] = 0.f; }
    int stride = gridDim.x * blockDim.x;
    for (int r = blockIdx.x * blockDim.x + threadIdx.x; r < rows; r += stride) {
        #pragma unroll
        for (int c = 0; c < C; ++c) {
            float x = v[r * C + c];
            s[c] += x; q[c] += x * x;
        }
    }
    #pragma unroll
    for (int c = 0; c < C; ++c) {
        float a = s[c], b = q[c];
        for (int off = 32; off > 0; off >>= 1) {
            a += __shfl_down(a, off, 64);
            b += __shfl_down(b, off, 64);
        }
        if ((threadIdx.x & 63) == 0) {
            atomAddF(&out[c], a);
            atomAddF(&out[C + c], b);
        }
    }
}

// ---------------- batchnorm apply ----------------
template<int C>
__global__ void normalize_kernel(const float* __restrict__ v, int rows,
                                 const float* __restrict__ stats,
                                 const float* __restrict__ g, const float* __restrict__ b,
                                 float* __restrict__ outp) {
    int idx = blockIdx.x * blockDim.x + threadIdx.x;
    int total = rows * C;
    if (idx >= total) return;
    int c = idx % C;
    float N = (float)rows;
    float m = stats[c] / N;
    float var = stats[C + c] / N - m * m;
    float sc = rsqrtf(var + BN_EPS) * g[c];
    outp[idx] = (v[idx] - m) * sc + b[c];
}

// ---------------- root transform: xout = xin @ W + bias ----------------
template<int CIN, int COUT>
__global__ void root_kernel(const float* __restrict__ xin, int nodes,
                            const float* __restrict__ w /*[CIN,COUT]*/,
                            const float* __restrict__ bias,
                            float* __restrict__ xout) {
    int n = blockIdx.x * blockDim.x + threadIdx.x;
    if (n >= nodes) return;
    float xi[CIN];
    #pragma unroll
    for (int i = 0; i < CIN; ++i) xi[i] = xin[n * CIN + i];
    #pragma unroll 4
    for (int o = 0; o < COUT; ++o) {
        float acc = bias[o];
        #pragma unroll
        for (int i = 0; i < CIN; ++i) acc += xi[i] * w[i * COUT + o];
        xout[n * COUT + o] = acc;
    }
}

// ---------------- fused NNConv edge kernel, (edge, o-chunk) decomposition ----------------
// grid = edge_blocks * NCHUNK; chunk = blockIdx.x % NCHUNK is wave-uniform so all
// w1/b1/w2/b2 accesses scalarize to s_load. h is recomputed per chunk (~4% extra FLOPs)
// in exchange for NCHUNK× more waves (round-2 version ran 1.5 waves/SIMD -> latency-bound).
template<int CIN, int COUT, int H, int OC>
__global__ __launch_bounds__(256, 4)
void conv_edge_kernel(
    const float* __restrict__ e_n,
    const int* __restrict__ src, const int* __restrict__ dst,
    const float* __restrict__ xin,
    const float* __restrict__ w1, const float* __restrict__ b1,
    const float* __restrict__ w2, const float* __restrict__ b2,
    float* __restrict__ xout, int n_edges)
{
    constexpr int EIN = 10;
    constexpr int NCHUNK = COUT / OC;
    int chunk = blockIdx.x % NCHUNK;                 // wave-uniform
    int e = (blockIdx.x / NCHUNK) * blockDim.x + threadIdx.x;
    if (e >= n_edges) return;
    int ob = chunk * OC;
    int s = src[e], d = dst[e];

    float ev[EIN];
    #pragma unroll
    for (int j = 0; j < EIN; ++j) ev[j] = e_n[(size_t)e * EIN + j];

    float h[H];
    #pragma unroll
    for (int k = 0; k < H; ++k) {
        float acc = b1[k];
        #pragma unroll
        for (int j = 0; j < EIN; ++j) acc += ev[j] * w1[j * H + k];
        h[k] = lrelu(acc);
    }

    float xr[CIN];
    const float* xrow = xin + (size_t)s * CIN;
    #pragma unroll
    for (int i = 0; i < CIN; ++i) xr[i] = xrow[i];

    float msg[OC];
    #pragma unroll
    for (int t = 0; t < OC; ++t) msg[t] = 0.f;

    #pragma unroll 1
    for (int i = 0; i < CIN; ++i) {
        float wa[OC];
        const float* b2p = b2 + i * COUT + ob;
        #pragma unroll
        for (int t = 0; t < OC; t += 4) {
            float4 bb = ld4(b2p + t);
            wa[t] = bb.x; wa[t + 1] = bb.y; wa[t + 2] = bb.z; wa[t + 3] = bb.w;
        }
        const float* w2p = w2 + i * COUT + ob;
        #pragma unroll
        for (int k = 0; k < H; ++k) {
            float hk = h[k];
            #pragma unroll
            for (int t = 0; t < OC; t += 4) {
                float4 w = ld4(w2p + (size_t)k * (CIN * COUT) + t);
                wa[t]     += hk * w.x;
                wa[t + 1] += hk * w.y;
                wa[t + 2] += hk * w.z;
                wa[t + 3] += hk * w.w;
            }
        }
        float xi = xr[i];
        #pragma unroll
        for (int t = 0; t < OC; ++t) msg[t] += xi * lrelu(wa[t]);
    }

    float* orow = xout + (size_t)d * COUT + ob;
    #pragma unroll
    for (int t = 0; t < OC; ++t) atomAddF(orow + t, msg[t]);
}

// ---------------- edge-prediction MLP: 138 -> 64 -> 32 -> 16 -> 8 -> 2 ----------------
// 2 lanes per edge: each lane accumulates a1 over half of the 138 inputs,
// one shfl_xor(lane^1) butterfly merges, tail layers computed redundantly.
__global__ __launch_bounds__(256, 3)
void mlp_kernel(const float* __restrict__ x2, const float* __restrict__ e_n,
                const int* __restrict__ src, const int* __restrict__ dst,
                const float* __restrict__ w1, const float* __restrict__ b1,
                const float* __restrict__ w2, const float* __restrict__ b2,
                const float* __restrict__ w3, const float* __restrict__ b3,
                const float* __restrict__ w4, const float* __restrict__ b4,
                const float* __restrict__ w5, const float* __restrict__ b5,
                float* __restrict__ out, int n_edges)
{
    int t = blockIdx.x * blockDim.x + threadIdx.x;
    int e = t >> 1;
    int half = t & 1;               // partner = lane^1, same wave
    if (e >= n_edges) return;
    int s = src[e], d = dst[e];

    float a1[64];
    #pragma unroll
    for (int j = 0; j < 64; ++j) a1[j] = half ? 0.f : b1[j];

    // half 0: rows 0..63 (x_src) + e_n[0..4];  half 1: rows 64..127 (x_dst) + e_n[5..9]
    const float* xrow = x2 + (size_t)(half ? d : s) * 64;
    const float* wbase = w1 + half * (64 * 64);
    #pragma unroll 1
    for (int i = 0; i < 64; ++i) {
        float xi = xrow[i];
        const float* wr = wbase + i * 64;
        #pragma unroll
        for (int j = 0; j < 64; ++j) a1[j] += xi * wr[j];
    }
    #pragma unroll 1
    for (int i2 = 0; i2 < 5; ++i2) {
        float xi = e_n[(size_t)e * 10 + half * 5 + i2];
        const float* wr = w1 + (128 + half * 5 + i2) * 64;
        #pragma unroll
        for (int j = 0; j < 64; ++j) a1[j] += xi * wr[j];
    }
    // merge halves + activation
    #pragma unroll
    for (int j = 0; j < 64; ++j) {
        a1[j] += __shfl_xor(a1[j], 1, 64);
        a1[j] = lrelu(a1[j]);
    }

    float a2[32];
    #pragma unroll
    for (int j = 0; j < 32; ++j) a2[j] = b2[j];
    #pragma unroll 2
    for (int i = 0; i < 64; ++i) {
        #pragma unroll
        for (int j = 0; j < 32; ++j) a2[j] += a1[i] * w2[i * 32 + j];
    }
    #pragma unroll
    for (int j = 0; j < 32; ++j) a2[j] = lrelu(a2[j]);

    float a3[16];
    #pragma unroll
    for (int j = 0; j < 16; ++j) a3[j] = b3[j];
    #pragma unroll
    for (int i = 0; i < 32; ++i) {
        #pragma unroll
        for (int j = 0; j < 16; ++j) a3[j] += a2[i] * w3[i * 16 + j];
    }
    #pragma unroll
    for (int j = 0; j < 16; ++j) a3[j] = lrelu(a3[j]);

    float a4[8];
    #pragma unroll
    for (int j = 0; j < 8; ++j) a4[j] = b4[j];
    #pragma unroll
    for (int i = 0; i < 16; ++i) {
        #pragma unroll
        for (int j = 0; j < 8; ++j) a4[j] += a3[i] * w4[i * 8 + j];
    }
    #pragma unroll
    for (int j = 0; j < 8; ++j) a4[j] = lrelu(a4[j]);

    float a5[2];
    #pragma unroll
    for (int j = 0; j < 2; ++j) a5[j] = b5[j];
    #pragma unroll
    for (int i = 0; i < 8; ++i) {
        #pragma unroll
        for (int j = 0; j < 2; ++j) a5[j] += a4[i] * w5[i * 2 + j];
    }
    if (half == 0) {
        out[(size_t)e * 2 + 0] = a5[0];
        out[(size_t)e * 2 + 1] = a5[1];
    }
}

// ---------------- launch ----------------
extern "C" void kernel_launch(void* const* d_in, const int* in_sizes, int n_in,
                              void* d_out, int out_size, void* d_ws, size_t ws_size,
                              hipStream_t stream)
{
    const float* x  = (const float*)d_in[0];
    const float* e  = (const float*)d_in[1];
    const int*   ei = (const int*)d_in[2];
    // d_in[3] = xbatch (unused)
    const float* bn_node_g = (const float*)d_in[4];
    const float* bn_node_b = (const float*)d_in[5];
    const float* bn_edge_g = (const float*)d_in[6];
    const float* bn_edge_b = (const float*)d_in[7];
    const float* nn1_w1 = (const float*)d_in[8];
    const float* nn1_b1 = (const float*)d_in[9];
    const float* nn1_w2 = (const float*)d_in[10];
    const float* nn1_b2 = (const float*)d_in[11];
    const float* nn2_w1 = (const float*)d_in[12];
    const float* nn2_b1 = (const float*)d_in[13];
    const float* nn2_w2 = (const float*)d_in[14];
    const float* nn2_b2 = (const float*)d_in[15];
    const float* l1_root = (const float*)d_in[16];
    const float* l1_bias = (const float*)d_in[17];
    const float* l2_root = (const float*)d_in[18];
    const float* l2_bias = (const float*)d_in[19];
    const float* mw1 = (const float*)d_in[20]; const float* mb1 = (const float*)d_in[21];
    const float* mw2 = (const float*)d_in[22]; const float* mb2 = (const float*)d_in[23];
    const float* mw3 = (const float*)d_in[24]; const float* mb3 = (const float*)d_in[25];
    const float* mw4 = (const float*)d_in[26]; const float* mb4 = (const float*)d_in[27];
    const float* mw5 = (const float*)d_in[28]; const float* mb5 = (const float*)d_in[29];

    const int* src = ei;
    const int* dst = ei + N_EDGES;

    float* ws = (float*)d_ws;
    float* stats_e = ws;            // 20 floats
    float* stats_x = ws + 32;       // 32 floats
    float* e_n = ws + 64;                       // 100000*10 = 1,000,000
    float* x_n = ws + 64 + 1000000;             // 20000*16  =   320,000
    float* x1  = ws + 64 + 1000000 + 320000;    // 20000*32  =   640,000
    float* x2  = ws + 64 + 1000000 + 320000 + 640000;  // 20000*64 = 1,280,000
    float* out = (float*)d_out;

    // zero the stats accumulators (ws is poisoned with 0xAA before every call)
    hipMemsetAsync(d_ws, 0, 256, stream);

    stats_kernel<10><<<200, 256, 0, stream>>>(e, N_EDGES, stats_e);
    stats_kernel<16><<<100, 256, 0, stream>>>(x, N_NODES, stats_x);

    normalize_kernel<10><<<(N_EDGES * 10 + 255) / 256, 256, 0, stream>>>(
        e, N_EDGES, stats_e, bn_edge_g, bn_edge_b, e_n);
    normalize_kernel<16><<<(N_NODES * 16 + 255) / 256, 256, 0, stream>>>(
        x, N_NODES, stats_x, bn_node_g, bn_node_b, x_n);

    const int EBLK = (N_EDGES + 255) / 256;

    // layer 1: x1 = x_n @ l1_root + l1_bias, then scatter-add messages (4 o-chunks)
    root_kernel<16, 32><<<(N_NODES + 255) / 256, 256, 0, stream>>>(x_n, N_NODES, l1_root, l1_bias, x1);
    conv_edge_kernel<16, 32, 16, 8><<<EBLK * 4, 256, 0, stream>>>(
        e_n, src, dst, x_n, nn1_w1, nn1_b1, nn1_w2, nn1_b2, x1, N_EDGES);

    // layer 2 (8 o-chunks)
    root_kernel<32, 64><<<(N_NODES + 255) / 256, 256, 0, stream>>>(x1, N_NODES, l2_root, l2_bias, x2);
    conv_edge_kernel<32, 64, 32, 8><<<EBLK * 8, 256, 0, stream>>>(
        e_n, src, dst, x1, nn2_w1, nn2_b1, nn2_w2, nn2_b2, x2, N_EDGES);

    // edge MLP: 2 lanes per edge
    mlp_kernel<<<(2 * N_EDGES + 255) / 256, 256, 0, stream>>>(
        x2, e_n, src, dst, mw1, mb1, mw2, mb2, mw3, mb3, mw4, mb4, mw5, mb5, out, N_EDGES);
}

// Round 4
// 695.908 us; speedup vs baseline: 1.9355x; 1.9355x over previous
//
#include <hip/hip_runtime.h>
#include <cstdint>

#define N_NODES 20000
#define N_EDGES 100000
#define BN_EPS 1e-5f

typedef __attribute__((ext_vector_type(8))) short short8;
typedef __attribute__((ext_vector_type(4))) float floatx4;

__device__ __forceinline__ float lrelu(float v) { return fmaxf(v, 0.1f * v); }
__device__ __forceinline__ float4 ld4(const float* p) { return *reinterpret_cast<const float4*>(p); }

__device__ __forceinline__ void atomAddF(float* p, float v) {
#if defined(__HIP_DEVICE_COMPILE__)
    unsafeAtomicAdd(p, v);   // hardware global_atomic_add_f32
#else
    atomicAdd(p, v);
#endif
}

// fp32 -> bf16 round-to-nearest-even
__device__ __forceinline__ unsigned short f2bf(float f) {
    union { float f; uint32_t u; } v; v.f = f;
    uint32_t r = v.u + 0x7fffu + ((v.u >> 16) & 1u);
    return (unsigned short)(r >> 16);
}
__device__ __forceinline__ uint32_t pack2(float a, float b) {
    return (uint32_t)f2bf(a) | ((uint32_t)f2bf(b) << 16);
}

// ---------------- column stats: sum + sumsq over rows ----------------
template<int C>
__global__ void stats_kernel(const float* __restrict__ v, int rows, float* __restrict__ out /*[2C]*/) {
    float s[C], q[C];
    #pragma unroll
    for (int c = 0; c < C; ++c) { s[c] = 0.f; q[c] = 0.f; }
    int stride = gridDim.x * blockDim.x;
    for (int r = blockIdx.x * blockDim.x + threadIdx.x; r < rows; r += stride) {
        #pragma unroll
        for (int c = 0; c < C; ++c) {
            float x = v[r * C + c];
            s[c] += x; q[c] += x * x;
        }
    }
    #pragma unroll
    for (int c = 0; c < C; ++c) {
        float a = s[c], b = q[c];
        for (int off = 32; off > 0; off >>= 1) {
            a += __shfl_down(a, off, 64);
            b += __shfl_down(b, off, 64);
        }
        if ((threadIdx.x & 63) == 0) {
            atomAddF(&out[c], a);
            atomAddF(&out[C + c], b);
        }
    }
}

// ---------------- batchnorm apply ----------------
template<int C>
__global__ void normalize_kernel(const float* __restrict__ v, int rows,
                                 const float* __restrict__ stats,
                                 const float* __restrict__ g, const float* __restrict__ b,
                                 float* __restrict__ outp) {
    int idx = blockIdx.x * blockDim.x + threadIdx.x;
    int total = rows * C;
    if (idx >= total) return;
    int c = idx % C;
    float N = (float)rows;
    float m = stats[c] / N;
    float var = stats[C + c] / N - m * m;
    float sc = rsqrtf(var + BN_EPS) * g[c];
    outp[idx] = (v[idx] - m) * sc + b[c];
}

// ---------------- root transform: xout = xin @ W + bias ----------------
template<int CIN, int COUT>
__global__ void root_kernel(const float* __restrict__ xin, int nodes,
                            const float* __restrict__ w /*[CIN,COUT]*/,
                            const float* __restrict__ bias,
                            float* __restrict__ xout) {
    int n = blockIdx.x * blockDim.x + threadIdx.x;
    if (n >= nodes) return;
    float xi[CIN];
    #pragma unroll
    for (int i = 0; i < CIN; ++i) xi[i] = xin[n * CIN + i];
    #pragma unroll 4
    for (int o = 0; o < COUT; ++o) {
        float acc = bias[o];
        #pragma unroll
        for (int i = 0; i < CIN; ++i) acc += xi[i] * w[i * COUT + o];
        xout[n * COUT + o] = acc;
    }
}

// ---------------- h-gen: h = lrelu(e_n @ w1 + b1) -> bf16 [E][32] (K-padded w/ zeros) ----
template<int H>
__global__ void hgen_kernel(const float* __restrict__ e_n,
                            const float* __restrict__ w1, const float* __restrict__ b1,
                            unsigned short* __restrict__ hbuf, int n_edges)
{
    int e = blockIdx.x * blockDim.x + threadIdx.x;
    if (e >= n_edges) return;
    float ev[10];
    #pragma unroll
    for (int j = 0; j < 10; ++j) ev[j] = e_n[(size_t)e * 10 + j];
    uint32_t pk[16];
    #pragma unroll
    for (int t = 0; t < 16; ++t) pk[t] = 0;
    #pragma unroll
    for (int k = 0; k < H; k += 2) {
        float a0 = b1[k], a1 = b1[k + 1];
        #pragma unroll
        for (int j = 0; j < 10; ++j) {
            a0 += ev[j] * w1[j * H + k];
            a1 += ev[j] * w1[j * H + k + 1];
        }
        pk[k >> 1] = pack2(lrelu(a0), lrelu(a1));
    }
    uint4* o = reinterpret_cast<uint4*>(hbuf + (size_t)e * 32);
    o[0] = make_uint4(pk[0], pk[1], pk[2], pk[3]);
    o[1] = make_uint4(pk[4], pk[5], pk[6], pk[7]);
    o[2] = make_uint4(pk[8], pk[9], pk[10], pk[11]);
    o[3] = make_uint4(pk[12], pk[13], pk[14], pk[15]);
}

// ---------------- weight transpose: w2[k][n] fp32 -> w2t[n][32] bf16 (k-contig, zero-pad) ----
template<int H, int NN>
__global__ void w2t_kernel(const float* __restrict__ w2, unsigned short* __restrict__ w2t) {
    int n = blockIdx.x * blockDim.x + threadIdx.x;
    if (n >= NN) return;
    uint32_t pk[16];
    #pragma unroll
    for (int t = 0; t < 16; ++t) pk[t] = 0;
    #pragma unroll
    for (int k = 0; k < H; k += 2)
        pk[k >> 1] = pack2(w2[(size_t)k * NN + n], w2[(size_t)(k + 1) * NN + n]);
    uint4* o = reinterpret_cast<uint4*>(w2t + (size_t)n * 32);
    o[0] = make_uint4(pk[0], pk[1], pk[2], pk[3]);
    o[1] = make_uint4(pk[4], pk[5], pk[6], pk[7]);
    o[2] = make_uint4(pk[8], pk[9], pk[10], pk[11]);
    o[3] = make_uint4(pk[12], pk[13], pk[14], pk[15]);
}

// ---------------- mlp w1 transpose: mw1[138][64] -> w1t[64][160] bf16 zero-padded ----
__global__ void w1t_kernel(const float* __restrict__ mw1, unsigned short* __restrict__ w1t) {
    int o = blockIdx.x * blockDim.x + threadIdx.x;
    if (o >= 64) return;
    for (int k = 0; k < 160; k += 2) {
        float a = (k < 138) ? mw1[(size_t)k * 64 + o] : 0.f;
        float b = (k + 1 < 138) ? mw1[(size_t)(k + 1) * 64 + o] : 0.f;
        *reinterpret_cast<uint32_t*>(w1t + (size_t)o * 160 + k) = pack2(a, b);
    }
}

// ---------------- fused NNConv via MFMA ----------------
// One wave = 16 edges. D[m][n] = sum_k w2t[nbase+m][k] * h[e0+n][k] ; C-init = b2 (bias).
// Epilogue: lrelu, *x[src][i], accumulate msg, 16 atomics/lane.
// 16x16x32 layouts (HW-verified): A[m=lane&15][k=quad*8+j], B[n=lane&15][k=quad*8+j],
// D col=lane&15 (n), row=quad*4+reg (m).
template<int CIN, int COUT>
__global__ __launch_bounds__(256, 3)
void conv_mfma_kernel(const unsigned short* __restrict__ hbuf,  // [E][32] bf16
                      const unsigned short* __restrict__ w2t,   // [CIN*COUT][32] bf16
                      const float* __restrict__ b2,             // [CIN*COUT]
                      const int* __restrict__ src, const int* __restrict__ dst,
                      const float* __restrict__ xin,            // [N][CIN]
                      float* __restrict__ xout, int n_edges)
{
    constexpr int NOT = COUT / 16;
    int wave = blockIdx.x * 4 + (threadIdx.x >> 6);
    int e0 = wave * 16;
    if (e0 >= n_edges) return;            // no barriers in this kernel
    int lane = threadIdx.x & 63;
    int el = lane & 15, quad = lane >> 4;
    int e = e0 + el;
    int s = src[e], d = dst[e];

    short8 bfrag = *reinterpret_cast<const short8*>(hbuf + (size_t)e * 32 + quad * 8);

    float xr[CIN];
    #pragma unroll
    for (int i = 0; i < CIN; i += 4) {
        float4 v = ld4(xin + (size_t)s * CIN + i);
        xr[i] = v.x; xr[i + 1] = v.y; xr[i + 2] = v.z; xr[i + 3] = v.w;
    }

    floatx4 msg[NOT];
    #pragma unroll
    for (int t = 0; t < NOT; ++t) msg[t] = (floatx4){0.f, 0.f, 0.f, 0.f};

    #pragma unroll 1
    for (int i = 0; i < CIN; ++i) {
        float xi = xr[i];
        #pragma unroll
        for (int ot = 0; ot < NOT; ++ot) {
            int nbase = i * COUT + ot * 16;
            short8 afrag = *reinterpret_cast<const short8*>(
                w2t + (size_t)(nbase + el) * 32 + quad * 8);
            float4 bb = ld4(b2 + nbase + quad * 4);
            floatx4 c = {bb.x, bb.y, bb.z, bb.w};
            c = __builtin_amdgcn_mfma_f32_16x16x32_bf16(afrag, bfrag, c, 0, 0, 0);
            #pragma unroll
            for (int r = 0; r < 4; ++r)
                msg[ot][r] += xi * lrelu(c[r]);
        }
    }

    float* orow = xout + (size_t)d * COUT;
    #pragma unroll
    for (int ot = 0; ot < NOT; ++ot) {
        #pragma unroll
        for (int r = 0; r < 4; ++r)
            atomAddF(orow + ot * 16 + quad * 4 + r, msg[ot][r]);
    }
}

// ---------------- edge MLP: layer1 via MFMA (K=160 padded), layers 2-5 per-thread ------
__global__ __launch_bounds__(256, 3)
void mlp_mfma_kernel(const float* __restrict__ x2, const float* __restrict__ e_n,
                     const int* __restrict__ src, const int* __restrict__ dst,
                     const unsigned short* __restrict__ w1t, const float* __restrict__ b1,
                     const float* __restrict__ w2, const float* __restrict__ b2,
                     const float* __restrict__ w3, const float* __restrict__ b3,
                     const float* __restrict__ w4, const float* __restrict__ b4,
                     const float* __restrict__ w5, const float* __restrict__ b5,
                     float* __restrict__ out, int n_edges)
{
    __shared__ unsigned short feat[64 * 168];   // [64 edges][160 k] bf16, stride 168 (bank swizzle)
    __shared__ float a1t[4 * 1096];             // per-wave [64 o][16 e] fp32, col stride 17, slab 1096

    int tid = threadIdx.x;
    int wv = tid >> 6, lane = tid & 63;
    int el = lane & 15, quad = lane >> 4;
    int eloc = wv * 16 + el;
    int e = blockIdx.x * 64 + eloc;
    int eS = (e < n_edges) ? e : (n_edges - 1);

    // ---- phase A: gather cat(x_src, x_dst, e_attr, 0-pad) -> feat LDS (bf16)
    {
        int row = (quad < 2) ? src[eS] : dst[eS];
        const float* rp = x2 + (size_t)row * 64 + (quad & 1) * 32;
        uint32_t pk[16];
        #pragma unroll
        for (int i = 0; i < 8; ++i) {
            float4 v = ld4(rp + i * 4);
            pk[i * 2]     = pack2(v.x, v.y);
            pk[i * 2 + 1] = pack2(v.z, v.w);
        }
        uint4* fp = reinterpret_cast<uint4*>(&feat[(size_t)eloc * 168 + quad * 32]);
        fp[0] = make_uint4(pk[0], pk[1], pk[2], pk[3]);
        fp[1] = make_uint4(pk[4], pk[5], pk[6], pk[7]);
        fp[2] = make_uint4(pk[8], pk[9], pk[10], pk[11]);
        fp[3] = make_uint4(pk[12], pk[13], pk[14], pk[15]);

        // tail k=128..159: e_n (10) + zeros (22); quad q covers k=128+q*8..+7
        uint32_t t0 = 0, t1 = 0, t2 = 0, t3 = 0;
        if (quad == 0) {
            const float* ep = e_n + (size_t)eS * 10;
            t0 = pack2(ep[0], ep[1]); t1 = pack2(ep[2], ep[3]);
            t2 = pack2(ep[4], ep[5]); t3 = pack2(ep[6], ep[7]);
        } else if (quad == 1) {
            const float* ep = e_n + (size_t)eS * 10;
            t0 = pack2(ep[8], ep[9]);
        }
        uint4* tp = reinterpret_cast<uint4*>(&feat[(size_t)eloc * 168 + 128 + quad * 8]);
        tp[0] = make_uint4(t0, t1, t2, t3);
    }
    __syncthreads();

    // ---- phase B: a1 = lrelu(feat @ w1 + b1) via 20 MFMA -> a1t LDS (transposed)
    {
        floatx4 acc[4];
        #pragma unroll
        for (int ot = 0; ot < 4; ++ot) {
            float4 bb = ld4(b1 + ot * 16 + quad * 4);
            acc[ot] = (floatx4){bb.x, bb.y, bb.z, bb.w};
        }
        #pragma unroll
        for (int ks = 0; ks < 5; ++ks) {
            short8 bf = *reinterpret_cast<const short8*>(
                &feat[(size_t)eloc * 168 + ks * 32 + quad * 8]);
            #pragma unroll
            for (int ot = 0; ot < 4; ++ot) {
                short8 af = *reinterpret_cast<const short8*>(
                    w1t + (size_t)(ot * 16 + el) * 160 + ks * 32 + quad * 8);
                acc[ot] = __builtin_amdgcn_mfma_f32_16x16x32_bf16(af, bf, acc[ot], 0, 0, 0);
            }
        }
        float* slab = &a1t[wv * 1096];
        #pragma unroll
        for (int ot = 0; ot < 4; ++ot) {
            #pragma unroll
            for (int r = 0; r < 4; ++r)
                slab[(ot * 16 + quad * 4 + r) * 17 + el] = lrelu(acc[ot][r]);
        }
    }
    __syncthreads();

    // ---- phase C: layers 2-5 per-thread (wave 0 handles all 64 edges of the block)
    if (tid < 64) {
        int ce = blockIdx.x * 64 + tid;
        const float* s2 = &a1t[(tid >> 4) * 1096];
        int cel = tid & 15;

        float a2[32];
        #pragma unroll
        for (int j = 0; j < 32; ++j) a2[j] = b2[j];
        #pragma unroll 1
        for (int i = 0; i < 64; ++i) {
            float ai = s2[i * 17 + cel];
            #pragma unroll
            for (int j = 0; j < 32; ++j) a2[j] += ai * w2[i * 32 + j];
        }
        #pragma unroll
        for (int j = 0; j < 32; ++j) a2[j] = lrelu(a2[j]);

        float a3[16];
        #pragma unroll
        for (int j = 0; j < 16; ++j) a3[j] = b3[j];
        #pragma unroll
        for (int i = 0; i < 32; ++i) {
            #pragma unroll
            for (int j = 0; j < 16; ++j) a3[j] += a2[i] * w3[i * 16 + j];
        }
        #pragma unroll
        for (int j = 0; j < 16; ++j) a3[j] = lrelu(a3[j]);

        float a4[8];
        #pragma unroll
        for (int j = 0; j < 8; ++j) a4[j] = b4[j];
        #pragma unroll
        for (int i = 0; i < 16; ++i) {
            #pragma unroll
            for (int j = 0; j < 8; ++j) a4[j] += a3[i] * w4[i * 8 + j];
        }
        #pragma unroll
        for (int j = 0; j < 8; ++j) a4[j] = lrelu(a4[j]);

        float o0 = b5[0], o1 = b5[1];
        #pragma unroll
        for (int i = 0; i < 8; ++i) {
            o0 += a4[i] * w5[i * 2 + 0];
            o1 += a4[i] * w5[i * 2 + 1];
        }
        if (ce < n_edges) {
            out[(size_t)ce * 2 + 0] = o0;
            out[(size_t)ce * 2 + 1] = o1;
        }
    }
}

// ---------------- launch ----------------
extern "C" void kernel_launch(void* const* d_in, const int* in_sizes, int n_in,
                              void* d_out, int out_size, void* d_ws, size_t ws_size,
                              hipStream_t stream)
{
    const float* x  = (const float*)d_in[0];
    const float* e  = (const float*)d_in[1];
    const int*   ei = (const int*)d_in[2];
    const float* bn_node_g = (const float*)d_in[4];
    const float* bn_node_b = (const float*)d_in[5];
    const float* bn_edge_g = (const float*)d_in[6];
    const float* bn_edge_b = (const float*)d_in[7];
    const float* nn1_w1 = (const float*)d_in[8];
    const float* nn1_b1 = (const float*)d_in[9];
    const float* nn1_w2 = (const float*)d_in[10];
    const float* nn1_b2 = (const float*)d_in[11];
    const float* nn2_w1 = (const float*)d_in[12];
    const float* nn2_b1 = (const float*)d_in[13];
    const float* nn2_w2 = (const float*)d_in[14];
    const float* nn2_b2 = (const float*)d_in[15];
    const float* l1_root = (const float*)d_in[16];
    const float* l1_bias = (const float*)d_in[17];
    const float* l2_root = (const float*)d_in[18];
    const float* l2_bias = (const float*)d_in[19];
    const float* mw1 = (const float*)d_in[20]; const float* mb1 = (const float*)d_in[21];
    const float* mw2 = (const float*)d_in[22]; const float* mb2 = (const float*)d_in[23];
    const float* mw3 = (const float*)d_in[24]; const float* mb3 = (const float*)d_in[25];
    const float* mw4 = (const float*)d_in[26]; const float* mb4 = (const float*)d_in[27];
    const float* mw5 = (const float*)d_in[28]; const float* mb5 = (const float*)d_in[29];

    const int* src = ei;
    const int* dst = ei + N_EDGES;

    float* ws = (float*)d_ws;
    float* stats_e = ws;                  // 20
    float* stats_x = ws + 32;             // 32
    float* e_n = ws + 64;                 // 1,000,000
    float* x_n = e_n + 1000000;           //   320,000
    float* x1  = x_n + 320000;            //   640,000
    float* x2  = x1 + 640000;             // 1,280,000
    unsigned short* h1   = (unsigned short*)(x2 + 1280000);  // 100000*32 bf16
    unsigned short* h2   = h1 + 3200000;                     // 100000*32 bf16
    unsigned short* w2t1 = h2 + 3200000;                     // 512*32
    unsigned short* w2t2 = w2t1 + 16384;                     // 2048*32
    unsigned short* w1t  = w2t2 + 65536;                     // 64*160
    float* out = (float*)d_out;

    hipMemsetAsync(d_ws, 0, 256, stream);   // stats accumulators

    // BN stats + normalize
    stats_kernel<10><<<200, 256, 0, stream>>>(e, N_EDGES, stats_e);
    stats_kernel<16><<<100, 256, 0, stream>>>(x, N_NODES, stats_x);
    normalize_kernel<10><<<(N_EDGES * 10 + 255) / 256, 256, 0, stream>>>(
        e, N_EDGES, stats_e, bn_edge_g, bn_edge_b, e_n);
    normalize_kernel<16><<<(N_NODES * 16 + 255) / 256, 256, 0, stream>>>(
        x, N_NODES, stats_x, bn_node_g, bn_node_b, x_n);

    // weight prep (independent of data order, cheap)
    w2t_kernel<16, 512><<<2, 256, 0, stream>>>(nn1_w2, w2t1);
    w2t_kernel<32, 2048><<<8, 256, 0, stream>>>(nn2_w2, w2t2);
    w1t_kernel<<<1, 64, 0, stream>>>(mw1, w1t);

    // per-edge hidden vectors (bf16, K-padded to 32)
    hgen_kernel<16><<<(N_EDGES + 255) / 256, 256, 0, stream>>>(e_n, nn1_w1, nn1_b1, h1, N_EDGES);
    hgen_kernel<32><<<(N_EDGES + 255) / 256, 256, 0, stream>>>(e_n, nn2_w1, nn2_b1, h2, N_EDGES);

    const int CONV_BLOCKS = (N_EDGES / 16 + 3) / 4;   // 6250 waves, 4 waves/block

    // layer 1
    root_kernel<16, 32><<<(N_NODES + 255) / 256, 256, 0, stream>>>(x_n, N_NODES, l1_root, l1_bias, x1);
    conv_mfma_kernel<16, 32><<<CONV_BLOCKS, 256, 0, stream>>>(
        h1, w2t1, nn1_b2, src, dst, x_n, x1, N_EDGES);

    // layer 2
    root_kernel<32, 64><<<(N_NODES + 255) / 256, 256, 0, stream>>>(x1, N_NODES, l2_root, l2_bias, x2);
    conv_mfma_kernel<32, 64><<<CONV_BLOCKS, 256, 0, stream>>>(
        h2, w2t2, nn2_b2, src, dst, x1, x2, N_EDGES);

    // edge MLP
    mlp_mfma_kernel<<<(N_EDGES + 63) / 64, 256, 0, stream>>>(
        x2, e_n, src, dst, w1t, mb1, mw2, mb2, mw3, mb3, mw4, mb4, mw5, mb5, out, N_EDGES);
}

// Round 5
// 452.230 us; speedup vs baseline: 2.9784x; 1.5388x over previous
//
#include <hip/hip_runtime.h>
#include <cstdint>

#define N_NODES 20000
#define N_EDGES 100000
#define BN_EPS 1e-5f

typedef __attribute__((ext_vector_type(8))) short short8;
typedef __attribute__((ext_vector_type(4))) float floatx4;

__device__ __forceinline__ float lrelu(float v) { return fmaxf(v, 0.1f * v); }
__device__ __forceinline__ float4 ld4(const float* p) { return *reinterpret_cast<const float4*>(p); }

__device__ __forceinline__ void atomAddF(float* p, float v) {
#if defined(__HIP_DEVICE_COMPILE__)
    unsafeAtomicAdd(p, v);   // hardware global_atomic_add_f32
#else
    atomicAdd(p, v);
#endif
}

// fp32 -> bf16 round-to-nearest-even
__device__ __forceinline__ unsigned short f2bf(float f) {
    union { float f; uint32_t u; } v; v.f = f;
    uint32_t r = v.u + 0x7fffu + ((v.u >> 16) & 1u);
    return (unsigned short)(r >> 16);
}
__device__ __forceinline__ uint32_t pack2(float a, float b) {
    return (uint32_t)f2bf(a) | ((uint32_t)f2bf(b) << 16);
}

// ---------------- column stats, C=10 (edge features) ----------------
// float2 loads; grid-stride is a multiple of 5 float2s so each thread owns a fixed
// column pair. Per-block LDS accumulate, ONE global atomic per column per block
// (round-4 version did 16000 same-address global atomics -> 166 us serialization).
__global__ void stats10_kernel(const float* __restrict__ v, int rows, float* __restrict__ out) {
    __shared__ float sh[20];
    if (threadIdx.x < 20) sh[threadIdx.x] = 0.f;
    __syncthreads();
    int nf2 = rows * 5;
    int stride = gridDim.x * blockDim.x;           // gridDim multiple of 5
    int g = blockIdx.x * blockDim.x + threadIdx.x;
    int c2 = g % 5;                                 // fixed column pair (2*c2, 2*c2+1)
    float s0 = 0.f, s1 = 0.f, q0 = 0.f, q1 = 0.f;
    const float2* p = reinterpret_cast<const float2*>(v);
    for (int i = g; i < nf2; i += stride) {
        float2 t = p[i];
        s0 += t.x; s1 += t.y; q0 += t.x * t.x; q1 += t.y * t.y;
    }
    atomicAdd(&sh[2 * c2], s0);
    atomicAdd(&sh[2 * c2 + 1], s1);
    atomicAdd(&sh[10 + 2 * c2], q0);
    atomicAdd(&sh[10 + 2 * c2 + 1], q1);
    __syncthreads();
    if (threadIdx.x < 20) atomAddF(&out[threadIdx.x], sh[threadIdx.x]);
}

// ---------------- column stats, C=16 (node features) ----------------
// float4 loads; lane's column group = (g&3)*4 is invariant under +4-lane shifts,
// so shfl_down by 32/16/8/4 reduces same-group lanes; lanes 0-3 hold group totals.
__global__ void stats16_kernel(const float* __restrict__ v, int rows, float* __restrict__ out) {
    __shared__ float sh[32];
    if (threadIdx.x < 32) sh[threadIdx.x] = 0.f;
    __syncthreads();
    int nf4 = rows * 4;
    int stride = gridDim.x * blockDim.x;
    int g = blockIdx.x * blockDim.x + threadIdx.x;
    int cg = (g & 3) * 4;
    float s[4] = {0.f, 0.f, 0.f, 0.f}, q[4] = {0.f, 0.f, 0.f, 0.f};
    const float4* p = reinterpret_cast<const float4*>(v);
    for (int i = g; i < nf4; i += stride) {
        float4 t = p[i];
        s[0] += t.x; s[1] += t.y; s[2] += t.z; s[3] += t.w;
        q[0] += t.x * t.x; q[1] += t.y * t.y; q[2] += t.z * t.z; q[3] += t.w * t.w;
    }
    #pragma unroll
    for (int off = 32; off >= 4; off >>= 1) {
        #pragma unroll
        for (int j = 0; j < 4; ++j) {
            s[j] += __shfl_down(s[j], off, 64);
            q[j] += __shfl_down(q[j], off, 64);
        }
    }
    if ((threadIdx.x & 63) < 4) {
        #pragma unroll
        for (int j = 0; j < 4; ++j) {
            atomicAdd(&sh[cg + j], s[j]);
            atomicAdd(&sh[16 + cg + j], q[j]);
        }
    }
    __syncthreads();
    if (threadIdx.x < 32) atomAddF(&out[threadIdx.x], sh[threadIdx.x]);
}

// ---------------- batchnorm apply ----------------
template<int C>
__global__ void normalize_kernel(const float* __restrict__ v, int rows,
                                 const float* __restrict__ stats,
                                 const float* __restrict__ g, const float* __restrict__ b,
                                 float* __restrict__ outp) {
    int idx = blockIdx.x * blockDim.x + threadIdx.x;
    int total = rows * C;
    if (idx >= total) return;
    int c = idx % C;
    float N = (float)rows;
    float m = stats[c] / N;
    float var = stats[C + c] / N - m * m;
    float sc = rsqrtf(var + BN_EPS) * g[c];
    outp[idx] = (v[idx] - m) * sc + b[c];
}

// ---------------- root transform: xout = xin @ W + bias ----------------
template<int CIN, int COUT>
__global__ void root_kernel(const float* __restrict__ xin, int nodes,
                            const float* __restrict__ w /*[CIN,COUT]*/,
                            const float* __restrict__ bias,
                            float* __restrict__ xout) {
    int n = blockIdx.x * blockDim.x + threadIdx.x;
    if (n >= nodes) return;
    float xi[CIN];
    #pragma unroll
    for (int i = 0; i < CIN; ++i) xi[i] = xin[n * CIN + i];
    #pragma unroll 4
    for (int o = 0; o < COUT; ++o) {
        float acc = bias[o];
        #pragma unroll
        for (int i = 0; i < CIN; ++i) acc += xi[i] * w[i * COUT + o];
        xout[n * COUT + o] = acc;
    }
}

// ---------------- fused h-gen for BOTH conv layers (one e_n read pass) ----------------
__global__ void hgen_both_kernel(const float* __restrict__ e_n,
                                 const float* __restrict__ w1a, const float* __restrict__ b1a,
                                 const float* __restrict__ w1b, const float* __restrict__ b1b,
                                 unsigned short* __restrict__ h1, unsigned short* __restrict__ h2,
                                 int n_edges)
{
    int e = blockIdx.x * blockDim.x + threadIdx.x;
    if (e >= n_edges) return;
    float ev[10];
    #pragma unroll
    for (int j = 0; j < 10; ++j) ev[j] = e_n[(size_t)e * 10 + j];

    // layer-1 hidden: H=16, zero-padded to K=32
    {
        uint32_t pk[16];
        #pragma unroll
        for (int t = 0; t < 16; ++t) pk[t] = 0;
        #pragma unroll
        for (int k = 0; k < 16; k += 2) {
            float a0 = b1a[k], a1 = b1a[k + 1];
            #pragma unroll
            for (int j = 0; j < 10; ++j) {
                a0 += ev[j] * w1a[j * 16 + k];
                a1 += ev[j] * w1a[j * 16 + k + 1];
            }
            pk[k >> 1] = pack2(lrelu(a0), lrelu(a1));
        }
        uint4* o = reinterpret_cast<uint4*>(h1 + (size_t)e * 32);
        o[0] = make_uint4(pk[0], pk[1], pk[2], pk[3]);
        o[1] = make_uint4(pk[4], pk[5], pk[6], pk[7]);
        o[2] = make_uint4(pk[8], pk[9], pk[10], pk[11]);
        o[3] = make_uint4(pk[12], pk[13], pk[14], pk[15]);
    }
    // layer-2 hidden: H=32
    {
        uint32_t pk[16];
        #pragma unroll
        for (int k = 0; k < 32; k += 2) {
            float a0 = b1b[k], a1 = b1b[k + 1];
            #pragma unroll
            for (int j = 0; j < 10; ++j) {
                a0 += ev[j] * w1b[j * 32 + k];
                a1 += ev[j] * w1b[j * 32 + k + 1];
            }
            pk[k >> 1] = pack2(lrelu(a0), lrelu(a1));
        }
        uint4* o = reinterpret_cast<uint4*>(h2 + (size_t)e * 32);
        o[0] = make_uint4(pk[0], pk[1], pk[2], pk[3]);
        o[1] = make_uint4(pk[4], pk[5], pk[6], pk[7]);
        o[2] = make_uint4(pk[8], pk[9], pk[10], pk[11]);
        o[3] = make_uint4(pk[12], pk[13], pk[14], pk[15]);
    }
}

// ---------------- weight transpose: w2[k][n] fp32 -> w2t[n][32] bf16 (k-contig, zero-pad) ----
template<int H, int NN>
__global__ void w2t_kernel(const float* __restrict__ w2, unsigned short* __restrict__ w2t) {
    int n = blockIdx.x * blockDim.x + threadIdx.x;
    if (n >= NN) return;
    uint32_t pk[16];
    #pragma unroll
    for (int t = 0; t < 16; ++t) pk[t] = 0;
    #pragma unroll
    for (int k = 0; k < H; k += 2)
        pk[k >> 1] = pack2(w2[(size_t)k * NN + n], w2[(size_t)(k + 1) * NN + n]);
    uint4* o = reinterpret_cast<uint4*>(w2t + (size_t)n * 32);
    o[0] = make_uint4(pk[0], pk[1], pk[2], pk[3]);
    o[1] = make_uint4(pk[4], pk[5], pk[6], pk[7]);
    o[2] = make_uint4(pk[8], pk[9], pk[10], pk[11]);
    o[3] = make_uint4(pk[12], pk[13], pk[14], pk[15]);
}

// ---------------- mlp w1 transpose: mw1[138][64] -> w1t[64][160] bf16 zero-padded ----
__global__ void w1t_kernel(const float* __restrict__ mw1, unsigned short* __restrict__ w1t) {
    int o = blockIdx.x * blockDim.x + threadIdx.x;
    if (o >= 64) return;
    for (int k = 0; k < 160; k += 2) {
        float a = (k < 138) ? mw1[(size_t)k * 64 + o] : 0.f;
        float b = (k + 1 < 138) ? mw1[(size_t)(k + 1) * 64 + o] : 0.f;
        *reinterpret_cast<uint32_t*>(w1t + (size_t)o * 160 + k) = pack2(a, b);
    }
}

// ---------------- fused NNConv via MFMA ----------------
// One wave = 16 edges. D[m][n] = sum_k w2t[nbase+m][k] * h[e0+n][k] ; C-init = b2 (bias).
// Epilogue: lrelu, *x[src][i], accumulate msg, 16 atomics/lane.
template<int CIN, int COUT>
__global__ __launch_bounds__(256, 3)
void conv_mfma_kernel(const unsigned short* __restrict__ hbuf,  // [E][32] bf16
                      const unsigned short* __restrict__ w2t,   // [CIN*COUT][32] bf16
                      const float* __restrict__ b2,             // [CIN*COUT]
                      const int* __restrict__ src, const int* __restrict__ dst,
                      const float* __restrict__ xin,            // [N][CIN]
                      float* __restrict__ xout, int n_edges)
{
    constexpr int NOT = COUT / 16;
    int wave = blockIdx.x * 4 + (threadIdx.x >> 6);
    int e0 = wave * 16;
    if (e0 >= n_edges) return;            // no barriers in this kernel
    int lane = threadIdx.x & 63;
    int el = lane & 15, quad = lane >> 4;
    int e = e0 + el;
    int s = src[e], d = dst[e];

    short8 bfrag = *reinterpret_cast<const short8*>(hbuf + (size_t)e * 32 + quad * 8);

    float xr[CIN];
    #pragma unroll
    for (int i = 0; i < CIN; i += 4) {
        float4 v = ld4(xin + (size_t)s * CIN + i);
        xr[i] = v.x; xr[i + 1] = v.y; xr[i + 2] = v.z; xr[i + 3] = v.w;
    }

    floatx4 msg[NOT];
    #pragma unroll
    for (int t = 0; t < NOT; ++t) msg[t] = (floatx4){0.f, 0.f, 0.f, 0.f};

    #pragma unroll 1
    for (int i = 0; i < CIN; ++i) {
        float xi = xr[i];
        #pragma unroll
        for (int ot = 0; ot < NOT; ++ot) {
            int nbase = i * COUT + ot * 16;
            short8 afrag = *reinterpret_cast<const short8*>(
                w2t + (size_t)(nbase + el) * 32 + quad * 8);
            float4 bb = ld4(b2 + nbase + quad * 4);
            floatx4 c = {bb.x, bb.y, bb.z, bb.w};
            c = __builtin_amdgcn_mfma_f32_16x16x32_bf16(afrag, bfrag, c, 0, 0, 0);
            #pragma unroll
            for (int r = 0; r < 4; ++r)
                msg[ot][r] += xi * lrelu(c[r]);
        }
    }

    float* orow = xout + (size_t)d * COUT;
    #pragma unroll
    for (int ot = 0; ot < NOT; ++ot) {
        #pragma unroll
        for (int r = 0; r < 4; ++r)
            atomAddF(orow + ot * 16 + quad * 4 + r, msg[ot][r]);
    }
}

// ---------------- edge MLP: layer1 via MFMA (K=160 padded), layers 2-5 per-thread ------
__global__ __launch_bounds__(256, 3)
void mlp_mfma_kernel(const float* __restrict__ x2, const float* __restrict__ e_n,
                     const int* __restrict__ src, const int* __restrict__ dst,
                     const unsigned short* __restrict__ w1t, const float* __restrict__ b1,
                     const float* __restrict__ w2, const float* __restrict__ b2,
                     const float* __restrict__ w3, const float* __restrict__ b3,
                     const float* __restrict__ w4, const float* __restrict__ b4,
                     const float* __restrict__ w5, const float* __restrict__ b5,
                     float* __restrict__ out, int n_edges)
{
    __shared__ unsigned short feat[64 * 168];   // [64 edges][160 k] bf16, stride 168
    __shared__ float a1t[4 * 1096];             // per-wave [64 o][16 e] fp32, col stride 17

    int tid = threadIdx.x;
    int wv = tid >> 6, lane = tid & 63;
    int el = lane & 15, quad = lane >> 4;
    int eloc = wv * 16 + el;
    int e = blockIdx.x * 64 + eloc;
    int eS = (e < n_edges) ? e : (n_edges - 1);

    // ---- phase A: gather cat(x_src, x_dst, e_attr, 0-pad) -> feat LDS (bf16)
    {
        int row = (quad < 2) ? src[eS] : dst[eS];
        const float* rp = x2 + (size_t)row * 64 + (quad & 1) * 32;
        uint32_t pk[16];
        #pragma unroll
        for (int i = 0; i < 8; ++i) {
            float4 v = ld4(rp + i * 4);
            pk[i * 2]     = pack2(v.x, v.y);
            pk[i * 2 + 1] = pack2(v.z, v.w);
        }
        uint4* fp = reinterpret_cast<uint4*>(&feat[(size_t)eloc * 168 + quad * 32]);
        fp[0] = make_uint4(pk[0], pk[1], pk[2], pk[3]);
        fp[1] = make_uint4(pk[4], pk[5], pk[6], pk[7]);
        fp[2] = make_uint4(pk[8], pk[9], pk[10], pk[11]);
        fp[3] = make_uint4(pk[12], pk[13], pk[14], pk[15]);

        uint32_t t0 = 0, t1 = 0, t2 = 0, t3 = 0;
        if (quad == 0) {
            const float* ep = e_n + (size_t)eS * 10;
            t0 = pack2(ep[0], ep[1]); t1 = pack2(ep[2], ep[3]);
            t2 = pack2(ep[4], ep[5]); t3 = pack2(ep[6], ep[7]);
        } else if (quad == 1) {
            const float* ep = e_n + (size_t)eS * 10;
            t0 = pack2(ep[8], ep[9]);
        }
        uint4* tp = reinterpret_cast<uint4*>(&feat[(size_t)eloc * 168 + 128 + quad * 8]);
        tp[0] = make_uint4(t0, t1, t2, t3);
    }
    __syncthreads();

    // ---- phase B: a1 = lrelu(feat @ w1 + b1) via 20 MFMA -> a1t LDS (transposed)
    {
        floatx4 acc[4];
        #pragma unroll
        for (int ot = 0; ot < 4; ++ot) {
            float4 bb = ld4(b1 + ot * 16 + quad * 4);
            acc[ot] = (floatx4){bb.x, bb.y, bb.z, bb.w};
        }
        #pragma unroll
        for (int ks = 0; ks < 5; ++ks) {
            short8 bf = *reinterpret_cast<const short8*>(
                &feat[(size_t)eloc * 168 + ks * 32 + quad * 8]);
            #pragma unroll
            for (int ot = 0; ot < 4; ++ot) {
                short8 af = *reinterpret_cast<const short8*>(
                    w1t + (size_t)(ot * 16 + el) * 160 + ks * 32 + quad * 8);
                acc[ot] = __builtin_amdgcn_mfma_f32_16x16x32_bf16(af, bf, acc[ot], 0, 0, 0);
            }
        }
        float* slab = &a1t[wv * 1096];
        #pragma unroll
        for (int ot = 0; ot < 4; ++ot) {
            #pragma unroll
            for (int r = 0; r < 4; ++r)
                slab[(ot * 16 + quad * 4 + r) * 17 + el] = lrelu(acc[ot][r]);
        }
    }
    __syncthreads();

    // ---- phase C: layers 2-5 per-thread (wave 0 handles all 64 edges of the block)
    if (tid < 64) {
        int ce = blockIdx.x * 64 + tid;
        const float* s2 = &a1t[(tid >> 4) * 1096];
        int cel = tid & 15;

        float a2[32];
        #pragma unroll
        for (int j = 0; j < 32; ++j) a2[j] = b2[j];
        #pragma unroll 1
        for (int i = 0; i < 64; ++i) {
            float ai = s2[i * 17 + cel];
            #pragma unroll
            for (int j = 0; j < 32; ++j) a2[j] += ai * w2[i * 32 + j];
        }
        #pragma unroll
        for (int j = 0; j < 32; ++j) a2[j] = lrelu(a2[j]);

        float a3[16];
        #pragma unroll
        for (int j = 0; j < 16; ++j) a3[j] = b3[j];
        #pragma unroll
        for (int i = 0; i < 32; ++i) {
            #pragma unroll
            for (int j = 0; j < 16; ++j) a3[j] += a2[i] * w3[i * 16 + j];
        }
        #pragma unroll
        for (int j = 0; j < 16; ++j) a3[j] = lrelu(a3[j]);

        float a4[8];
        #pragma unroll
        for (int j = 0; j < 8; ++j) a4[j] = b4[j];
        #pragma unroll
        for (int i = 0; i < 16; ++i) {
            #pragma unroll
            for (int j = 0; j < 8; ++j) a4[j] += a3[i] * w4[i * 8 + j];
        }
        #pragma unroll
        for (int j = 0; j < 8; ++j) a4[j] = lrelu(a4[j]);

        float o0 = b5[0], o1 = b5[1];
        #pragma unroll
        for (int i = 0; i < 8; ++i) {
            o0 += a4[i] * w5[i * 2 + 0];
            o1 += a4[i] * w5[i * 2 + 1];
        }
        if (ce < n_edges) {
            out[(size_t)ce * 2 + 0] = o0;
            out[(size_t)ce * 2 + 1] = o1;
        }
    }
}

// ---------------- launch ----------------
extern "C" void kernel_launch(void* const* d_in, const int* in_sizes, int n_in,
                              void* d_out, int out_size, void* d_ws, size_t ws_size,
                              hipStream_t stream)
{
    const float* x  = (const float*)d_in[0];
    const float* e  = (const float*)d_in[1];
    const int*   ei = (const int*)d_in[2];
    const float* bn_node_g = (const float*)d_in[4];
    const float* bn_node_b = (const float*)d_in[5];
    const float* bn_edge_g = (const float*)d_in[6];
    const float* bn_edge_b = (const float*)d_in[7];
    const float* nn1_w1 = (const float*)d_in[8];
    const float* nn1_b1 = (const float*)d_in[9];
    const float* nn1_w2 = (const float*)d_in[10];
    const float* nn1_b2 = (const float*)d_in[11];
    const float* nn2_w1 = (const float*)d_in[12];
    const float* nn2_b1 = (const float*)d_in[13];
    const float* nn2_w2 = (const float*)d_in[14];
    const float* nn2_b2 = (const float*)d_in[15];
    const float* l1_root = (const float*)d_in[16];
    const float* l1_bias = (const float*)d_in[17];
    const float* l2_root = (const float*)d_in[18];
    const float* l2_bias = (const float*)d_in[19];
    const float* mw1 = (const float*)d_in[20]; const float* mb1 = (const float*)d_in[21];
    const float* mw2 = (const float*)d_in[22]; const float* mb2 = (const float*)d_in[23];
    const float* mw3 = (const float*)d_in[24]; const float* mb3 = (const float*)d_in[25];
    const float* mw4 = (const float*)d_in[26]; const float* mb4 = (const float*)d_in[27];
    const float* mw5 = (const float*)d_in[28]; const float* mb5 = (const float*)d_in[29];

    const int* src = ei;
    const int* dst = ei + N_EDGES;

    float* ws = (float*)d_ws;
    float* stats_e = ws;                  // 20
    float* stats_x = ws + 32;             // 32
    float* e_n = ws + 64;                 // 1,000,000
    float* x_n = e_n + 1000000;           //   320,000
    float* x1  = x_n + 320000;            //   640,000
    float* x2  = x1 + 640000;             // 1,280,000
    unsigned short* h1   = (unsigned short*)(x2 + 1280000);  // 100000*32 bf16
    unsigned short* h2   = h1 + 3200000;                     // 100000*32 bf16
    unsigned short* w2t1 = h2 + 3200000;                     // 512*32
    unsigned short* w2t2 = w2t1 + 16384;                     // 2048*32
    unsigned short* w1t  = w2t2 + 65536;                     // 64*160
    float* out = (float*)d_out;

    hipMemsetAsync(d_ws, 0, 256, stream);   // stats accumulators

    // BN stats (two-stage reduction) + normalize
    stats10_kernel<<<120, 256, 0, stream>>>(e, N_EDGES, stats_e);   // 120 % 5 == 0
    stats16_kernel<<<120, 256, 0, stream>>>(x, N_NODES, stats_x);
    normalize_kernel<10><<<(N_EDGES * 10 + 255) / 256, 256, 0, stream>>>(
        e, N_EDGES, stats_e, bn_edge_g, bn_edge_b, e_n);
    normalize_kernel<16><<<(N_NODES * 16 + 255) / 256, 256, 0, stream>>>(
        x, N_NODES, stats_x, bn_node_g, bn_node_b, x_n);

    // weight prep
    w2t_kernel<16, 512><<<2, 256, 0, stream>>>(nn1_w2, w2t1);
    w2t_kernel<32, 2048><<<8, 256, 0, stream>>>(nn2_w2, w2t2);
    w1t_kernel<<<1, 64, 0, stream>>>(mw1, w1t);

    // per-edge hidden vectors for both conv layers (single e_n pass)
    hgen_both_kernel<<<(N_EDGES + 255) / 256, 256, 0, stream>>>(
        e_n, nn1_w1, nn1_b1, nn2_w1, nn2_b1, h1, h2, N_EDGES);

    const int CONV_BLOCKS = (N_EDGES / 16 + 3) / 4;   // 6250 waves, 4 waves/block

    // layer 1
    root_kernel<16, 32><<<(N_NODES + 255) / 256, 256, 0, stream>>>(x_n, N_NODES, l1_root, l1_bias, x1);
    conv_mfma_kernel<16, 32><<<CONV_BLOCKS, 256, 0, stream>>>(
        h1, w2t1, nn1_b2, src, dst, x_n, x1, N_EDGES);

    // layer 2
    root_kernel<32, 64><<<(N_NODES + 255) / 256, 256, 0, stream>>>(x1, N_NODES, l2_root, l2_bias, x2);
    conv_mfma_kernel<32, 64><<<CONV_BLOCKS, 256, 0, stream>>>(
        h2, w2t2, nn2_b2, src, dst, x1, x2, N_EDGES);

    // edge MLP
    mlp_mfma_kernel<<<(N_EDGES + 63) / 64, 256, 0, stream>>>(
        x2, e_n, src, dst, w1t, mb1, mw2, mb2, mw3, mb3, mw4, mb4, mw5, mb5, out, N_EDGES);
}

// Round 6
// 448.340 us; speedup vs baseline: 3.0043x; 1.0087x over previous
//
#include <hip/hip_runtime.h>
#include <cstdint>

#define N_NODES 20000
#define N_EDGES 100000
#define BN_EPS 1e-5f

typedef __attribute__((ext_vector_type(8))) short short8;
typedef __attribute__((ext_vector_type(4))) float floatx4;

__device__ __forceinline__ float lrelu(float v) { return fmaxf(v, 0.1f * v); }
__device__ __forceinline__ float4 ld4(const float* p) { return *reinterpret_cast<const float4*>(p); }

__device__ __forceinline__ void atomAddF(float* p, float v) {
#if defined(__HIP_DEVICE_COMPILE__)
    unsafeAtomicAdd(p, v);
#else
    atomicAdd(p, v);
#endif
}

// fp32 -> bf16 round-to-nearest-even
__device__ __forceinline__ unsigned short f2bf(float f) {
    union { float f; uint32_t u; } v; v.f = f;
    uint32_t r = v.u + 0x7fffu + ((v.u >> 16) & 1u);
    return (unsigned short)(r >> 16);
}
__device__ __forceinline__ uint32_t pack2(float a, float b) {
    return (uint32_t)f2bf(a) | ((uint32_t)f2bf(b) << 16);
}

// ---------------- column stats, C=10 ----------------
__global__ void stats10_kernel(const float* __restrict__ v, int rows, float* __restrict__ out) {
    __shared__ float sh[20];
    if (threadIdx.x < 20) sh[threadIdx.x] = 0.f;
    __syncthreads();
    int nf2 = rows * 5;
    int stride = gridDim.x * blockDim.x;           // gridDim multiple of 5
    int g = blockIdx.x * blockDim.x + threadIdx.x;
    int c2 = g % 5;
    float s0 = 0.f, s1 = 0.f, q0 = 0.f, q1 = 0.f;
    const float2* p = reinterpret_cast<const float2*>(v);
    for (int i = g; i < nf2; i += stride) {
        float2 t = p[i];
        s0 += t.x; s1 += t.y; q0 += t.x * t.x; q1 += t.y * t.y;
    }
    atomicAdd(&sh[2 * c2], s0);
    atomicAdd(&sh[2 * c2 + 1], s1);
    atomicAdd(&sh[10 + 2 * c2], q0);
    atomicAdd(&sh[10 + 2 * c2 + 1], q1);
    __syncthreads();
    if (threadIdx.x < 20) atomAddF(&out[threadIdx.x], sh[threadIdx.x]);
}

// ---------------- column stats, C=16 ----------------
__global__ void stats16_kernel(const float* __restrict__ v, int rows, float* __restrict__ out) {
    __shared__ float sh[32];
    if (threadIdx.x < 32) sh[threadIdx.x] = 0.f;
    __syncthreads();
    int nf4 = rows * 4;
    int stride = gridDim.x * blockDim.x;
    int g = blockIdx.x * blockDim.x + threadIdx.x;
    int cg = (g & 3) * 4;
    float s[4] = {0.f, 0.f, 0.f, 0.f}, q[4] = {0.f, 0.f, 0.f, 0.f};
    const float4* p = reinterpret_cast<const float4*>(v);
    for (int i = g; i < nf4; i += stride) {
        float4 t = p[i];
        s[0] += t.x; s[1] += t.y; s[2] += t.z; s[3] += t.w;
        q[0] += t.x * t.x; q[1] += t.y * t.y; q[2] += t.z * t.z; q[3] += t.w * t.w;
    }
    #pragma unroll
    for (int off = 32; off >= 4; off >>= 1) {
        #pragma unroll
        for (int j = 0; j < 4; ++j) {
            s[j] += __shfl_down(s[j], off, 64);
            q[j] += __shfl_down(q[j], off, 64);
        }
    }
    if ((threadIdx.x & 63) < 4) {
        #pragma unroll
        for (int j = 0; j < 4; ++j) {
            atomicAdd(&sh[cg + j], s[j]);
            atomicAdd(&sh[16 + cg + j], q[j]);
        }
    }
    __syncthreads();
    if (threadIdx.x < 32) atomAddF(&out[threadIdx.x], sh[threadIdx.x]);
}

// ---------------- batchnorm apply ----------------
template<int C>
__global__ void normalize_kernel(const float* __restrict__ v, int rows,
                                 const float* __restrict__ stats,
                                 const float* __restrict__ g, const float* __restrict__ b,
                                 float* __restrict__ outp) {
    int idx = blockIdx.x * blockDim.x + threadIdx.x;
    int total = rows * C;
    if (idx >= total) return;
    int c = idx % C;
    float N = (float)rows;
    float m = stats[c] / N;
    float var = stats[C + c] / N - m * m;
    float sc = rsqrtf(var + BN_EPS) * g[c];
    outp[idx] = (v[idx] - m) * sc + b[c];
}

// ---------------- CSR-by-dst build ----------------
__global__ void hist_kernel(const int* __restrict__ dst, int* __restrict__ counts, int n) {
    int i = blockIdx.x * blockDim.x + threadIdx.x;
    if (i < n) atomicAdd(&counts[dst[i]], 1);
}

__global__ void scan_kernel(const int* __restrict__ counts, int* __restrict__ starts,
                            int* __restrict__ cursor, int n) {
    __shared__ int part[256];
    const int CH = (n + 255) / 256;
    int t = threadIdx.x;
    int lo = t * CH, hi = min(lo + CH, n);
    int s = 0;
    for (int i = lo; i < hi; ++i) s += counts[i];
    part[t] = s;
    __syncthreads();
    if (t == 0) {
        int acc = 0;
        for (int i = 0; i < 256; ++i) { int v = part[i]; part[i] = acc; acc += v; }
    }
    __syncthreads();
    int acc = part[t];
    for (int i = lo; i < hi; ++i) {
        starts[i] = acc; cursor[i] = acc; acc += counts[i];
    }
}

__global__ void scatter_kernel(const int* __restrict__ dst, int* __restrict__ cursor,
                               int* __restrict__ elist, int n) {
    int i = blockIdx.x * blockDim.x + threadIdx.x;
    if (i < n) {
        int p = atomicAdd(&cursor[dst[i]], 1);
        elist[p] = i;
    }
}

// ---------------- root transform: xout = xin @ W + bias ----------------
template<int CIN, int COUT>
__global__ void root_kernel(const float* __restrict__ xin, int nodes,
                            const float* __restrict__ w, const float* __restrict__ bias,
                            float* __restrict__ xout) {
    int n = blockIdx.x * blockDim.x + threadIdx.x;
    if (n >= nodes) return;
    float xi[CIN];
    #pragma unroll
    for (int i = 0; i < CIN; ++i) xi[i] = xin[n * CIN + i];
    #pragma unroll 4
    for (int o = 0; o < COUT; ++o) {
        float acc = bias[o];
        #pragma unroll
        for (int i = 0; i < CIN; ++i) acc += xi[i] * w[i * COUT + o];
        xout[n * COUT + o] = acc;
    }
}

// ---------------- fused h-gen for BOTH conv layers ----------------
__global__ void hgen_both_kernel(const float* __restrict__ e_n,
                                 const float* __restrict__ w1a, const float* __restrict__ b1a,
                                 const float* __restrict__ w1b, const float* __restrict__ b1b,
                                 unsigned short* __restrict__ h1, unsigned short* __restrict__ h2,
                                 int n_edges)
{
    int e = blockIdx.x * blockDim.x + threadIdx.x;
    if (e >= n_edges) return;
    float ev[10];
    #pragma unroll
    for (int j = 0; j < 10; ++j) ev[j] = e_n[(size_t)e * 10 + j];

    {
        uint32_t pk[16];
        #pragma unroll
        for (int t = 0; t < 16; ++t) pk[t] = 0;
        #pragma unroll
        for (int k = 0; k < 16; k += 2) {
            float a0 = b1a[k], a1 = b1a[k + 1];
            #pragma unroll
            for (int j = 0; j < 10; ++j) {
                a0 += ev[j] * w1a[j * 16 + k];
                a1 += ev[j] * w1a[j * 16 + k + 1];
            }
            pk[k >> 1] = pack2(lrelu(a0), lrelu(a1));
        }
        uint4* o = reinterpret_cast<uint4*>(h1 + (size_t)e * 32);
        o[0] = make_uint4(pk[0], pk[1], pk[2], pk[3]);
        o[1] = make_uint4(pk[4], pk[5], pk[6], pk[7]);
        o[2] = make_uint4(pk[8], pk[9], pk[10], pk[11]);
        o[3] = make_uint4(pk[12], pk[13], pk[14], pk[15]);
    }
    {
        uint32_t pk[16];
        #pragma unroll
        for (int k = 0; k < 32; k += 2) {
            float a0 = b1b[k], a1 = b1b[k + 1];
            #pragma unroll
            for (int j = 0; j < 10; ++j) {
                a0 += ev[j] * w1b[j * 32 + k];
                a1 += ev[j] * w1b[j * 32 + k + 1];
            }
            pk[k >> 1] = pack2(lrelu(a0), lrelu(a1));
        }
        uint4* o = reinterpret_cast<uint4*>(h2 + (size_t)e * 32);
        o[0] = make_uint4(pk[0], pk[1], pk[2], pk[3]);
        o[1] = make_uint4(pk[4], pk[5], pk[6], pk[7]);
        o[2] = make_uint4(pk[8], pk[9], pk[10], pk[11]);
        o[3] = make_uint4(pk[12], pk[13], pk[14], pk[15]);
    }
}

// ---------------- weight transposes ----------------
template<int H, int NN>
__global__ void w2t_kernel(const float* __restrict__ w2, unsigned short* __restrict__ w2t) {
    int n = blockIdx.x * blockDim.x + threadIdx.x;
    if (n >= NN) return;
    uint32_t pk[16];
    #pragma unroll
    for (int t = 0; t < 16; ++t) pk[t] = 0;
    #pragma unroll
    for (int k = 0; k < H; k += 2)
        pk[k >> 1] = pack2(w2[(size_t)k * NN + n], w2[(size_t)(k + 1) * NN + n]);
    uint4* o = reinterpret_cast<uint4*>(w2t + (size_t)n * 32);
    o[0] = make_uint4(pk[0], pk[1], pk[2], pk[3]);
    o[1] = make_uint4(pk[4], pk[5], pk[6], pk[7]);
    o[2] = make_uint4(pk[8], pk[9], pk[10], pk[11]);
    o[3] = make_uint4(pk[12], pk[13], pk[14], pk[15]);
}

__global__ void w1t_kernel(const float* __restrict__ mw1, unsigned short* __restrict__ w1t) {
    int o = blockIdx.x * blockDim.x + threadIdx.x;
    if (o >= 64) return;
    for (int k = 0; k < 160; k += 2) {
        float a = (k < 138) ? mw1[(size_t)k * 64 + o] : 0.f;
        float b = (k + 1 < 138) ? mw1[(size_t)(k + 1) * 64 + o] : 0.f;
        *reinterpret_cast<uint32_t*>(w1t + (size_t)o * 160 + k) = pack2(a, b);
    }
}

// ---------------- NNConv message kernel via MFMA: plain stores, no atomics ----------------
template<int CIN, int COUT>
__global__ __launch_bounds__(256, 3)
void conv_mfma_kernel(const unsigned short* __restrict__ hbuf,  // [E][32] bf16
                      const unsigned short* __restrict__ w2t,   // [CIN*COUT][32] bf16
                      const float* __restrict__ b2,
                      const int* __restrict__ src,
                      const float* __restrict__ xin,            // [N][CIN]
                      float* __restrict__ msgbuf,               // [E][COUT]
                      int n_edges)
{
    constexpr int NOT = COUT / 16;
    int wave = blockIdx.x * 4 + (threadIdx.x >> 6);
    int e0 = wave * 16;
    if (e0 >= n_edges) return;
    int lane = threadIdx.x & 63;
    int el = lane & 15, quad = lane >> 4;
    int e = e0 + el;
    int s = src[e];

    short8 bfrag = *reinterpret_cast<const short8*>(hbuf + (size_t)e * 32 + quad * 8);

    float xr[CIN];
    #pragma unroll
    for (int i = 0; i < CIN; i += 4) {
        float4 v = ld4(xin + (size_t)s * CIN + i);
        xr[i] = v.x; xr[i + 1] = v.y; xr[i + 2] = v.z; xr[i + 3] = v.w;
    }

    floatx4 msg[NOT];
    #pragma unroll
    for (int t = 0; t < NOT; ++t) msg[t] = (floatx4){0.f, 0.f, 0.f, 0.f};

    #pragma unroll 1
    for (int i = 0; i < CIN; ++i) {
        float xi = xr[i];
        #pragma unroll
        for (int ot = 0; ot < NOT; ++ot) {
            int nbase = i * COUT + ot * 16;
            short8 afrag = *reinterpret_cast<const short8*>(
                w2t + (size_t)(nbase + el) * 32 + quad * 8);
            float4 bb = ld4(b2 + nbase + quad * 4);
            floatx4 c = {bb.x, bb.y, bb.z, bb.w};
            c = __builtin_amdgcn_mfma_f32_16x16x32_bf16(afrag, bfrag, c, 0, 0, 0);
            #pragma unroll
            for (int r = 0; r < 4; ++r)
                msg[ot][r] += xi * lrelu(c[r]);
        }
    }

    float* orow = msgbuf + (size_t)e * COUT;
    #pragma unroll
    for (int ot = 0; ot < NOT; ++ot)
        *reinterpret_cast<float4*>(orow + ot * 16 + quad * 4) =
            make_float4(msg[ot][0], msg[ot][1], msg[ot][2], msg[ot][3]);
}

// ---------------- CSR gather: xout[n] += sum_{e in in(n)} msg[e] ----------------
template<int C>
__global__ __launch_bounds__(256)
void gather_kernel(const float* __restrict__ msg,
                   const int* __restrict__ starts, const int* __restrict__ counts,
                   const int* __restrict__ elist,
                   float* __restrict__ xout, int nodes)
{
    constexpr int NPW = 64 / C;
    int wv = blockIdx.x * 4 + (threadIdx.x >> 6);
    int lane = threadIdx.x & 63;
    int node = wv * NPW + lane / C;
    int ch = lane % C;
    if (node >= nodes) return;
    float acc = xout[(size_t)node * C + ch];
    int s0 = starts[node], cnt = counts[node];
    for (int i = 0; i < cnt; ++i) {
        int eid = elist[s0 + i];
        acc += msg[(size_t)eid * C + ch];
    }
    xout[(size_t)node * C + ch] = acc;
}

// ---------------- edge MLP: layer1 via MFMA, layers 2-5 per-thread ----------------
__global__ __launch_bounds__(256, 3)
void mlp_mfma_kernel(const float* __restrict__ x2, const float* __restrict__ e_n,
                     const int* __restrict__ src, const int* __restrict__ dst,
                     const unsigned short* __restrict__ w1t, const float* __restrict__ b1,
                     const float* __restrict__ w2, const float* __restrict__ b2,
                     const float* __restrict__ w3, const float* __restrict__ b3,
                     const float* __restrict__ w4, const float* __restrict__ b4,
                     const float* __restrict__ w5, const float* __restrict__ b5,
                     float* __restrict__ out, int n_edges)
{
    __shared__ unsigned short feat[64 * 168];
    __shared__ float a1t[4 * 1096];

    int tid = threadIdx.x;
    int wv = tid >> 6, lane = tid & 63;
    int el = lane & 15, quad = lane >> 4;
    int eloc = wv * 16 + el;
    int e = blockIdx.x * 64 + eloc;
    int eS = (e < n_edges) ? e : (n_edges - 1);

    {
        int row = (quad < 2) ? src[eS] : dst[eS];
        const float* rp = x2 + (size_t)row * 64 + (quad & 1) * 32;
        uint32_t pk[16];
        #pragma unroll
        for (int i = 0; i < 8; ++i) {
            float4 v = ld4(rp + i * 4);
            pk[i * 2]     = pack2(v.x, v.y);
            pk[i * 2 + 1] = pack2(v.z, v.w);
        }
        uint4* fp = reinterpret_cast<uint4*>(&feat[(size_t)eloc * 168 + quad * 32]);
        fp[0] = make_uint4(pk[0], pk[1], pk[2], pk[3]);
        fp[1] = make_uint4(pk[4], pk[5], pk[6], pk[7]);
        fp[2] = make_uint4(pk[8], pk[9], pk[10], pk[11]);
        fp[3] = make_uint4(pk[12], pk[13], pk[14], pk[15]);

        uint32_t t0 = 0, t1 = 0, t2 = 0, t3 = 0;
        if (quad == 0) {
            const float* ep = e_n + (size_t)eS * 10;
            t0 = pack2(ep[0], ep[1]); t1 = pack2(ep[2], ep[3]);
            t2 = pack2(ep[4], ep[5]); t3 = pack2(ep[6], ep[7]);
        } else if (quad == 1) {
            const float* ep = e_n + (size_t)eS * 10;
            t0 = pack2(ep[8], ep[9]);
        }
        uint4* tp = reinterpret_cast<uint4*>(&feat[(size_t)eloc * 168 + 128 + quad * 8]);
        tp[0] = make_uint4(t0, t1, t2, t3);
    }
    __syncthreads();

    {
        floatx4 acc[4];
        #pragma unroll
        for (int ot = 0; ot < 4; ++ot) {
            float4 bb = ld4(b1 + ot * 16 + quad * 4);
            acc[ot] = (floatx4){bb.x, bb.y, bb.z, bb.w};
        }
        #pragma unroll
        for (int ks = 0; ks < 5; ++ks) {
            short8 bf = *reinterpret_cast<const short8*>(
                &feat[(size_t)eloc * 168 + ks * 32 + quad * 8]);
            #pragma unroll
            for (int ot = 0; ot < 4; ++ot) {
                short8 af = *reinterpret_cast<const short8*>(
                    w1t + (size_t)(ot * 16 + el) * 160 + ks * 32 + quad * 8);
                acc[ot] = __builtin_amdgcn_mfma_f32_16x16x32_bf16(af, bf, acc[ot], 0, 0, 0);
            }
        }
        float* slab = &a1t[wv * 1096];
        #pragma unroll
        for (int ot = 0; ot < 4; ++ot) {
            #pragma unroll
            for (int r = 0; r < 4; ++r)
                slab[(ot * 16 + quad * 4 + r) * 17 + el] = lrelu(acc[ot][r]);
        }
    }
    __syncthreads();

    if (tid < 64) {
        int ce = blockIdx.x * 64 + tid;
        const float* s2 = &a1t[(tid >> 4) * 1096];
        int cel = tid & 15;

        float a2[32];
        #pragma unroll
        for (int j = 0; j < 32; ++j) a2[j] = b2[j];
        #pragma unroll 1
        for (int i = 0; i < 64; ++i) {
            float ai = s2[i * 17 + cel];
            #pragma unroll
            for (int j = 0; j < 32; ++j) a2[j] += ai * w2[i * 32 + j];
        }
        #pragma unroll
        for (int j = 0; j < 32; ++j) a2[j] = lrelu(a2[j]);

        float a3[16];
        #pragma unroll
        for (int j = 0; j < 16; ++j) a3[j] = b3[j];
        #pragma unroll
        for (int i = 0; i < 32; ++i) {
            #pragma unroll
            for (int j = 0; j < 16; ++j) a3[j] += a2[i] * w3[i * 16 + j];
        }
        #pragma unroll
        for (int j = 0; j < 16; ++j) a3[j] = lrelu(a3[j]);

        float a4[8];
        #pragma unroll
        for (int j = 0; j < 8; ++j) a4[j] = b4[j];
        #pragma unroll
        for (int i = 0; i < 16; ++i) {
            #pragma unroll
            for (int j = 0; j < 8; ++j) a4[j] += a3[i] * w4[i * 8 + j];
        }
        #pragma unroll
        for (int j = 0; j < 8; ++j) a4[j] = lrelu(a4[j]);

        float o0 = b5[0], o1 = b5[1];
        #pragma unroll
        for (int i = 0; i < 8; ++i) {
            o0 += a4[i] * w5[i * 2 + 0];
            o1 += a4[i] * w5[i * 2 + 1];
        }
        if (ce < n_edges) {
            out[(size_t)ce * 2 + 0] = o0;
            out[(size_t)ce * 2 + 1] = o1;
        }
    }
}

// ---------------- launch ----------------
extern "C" void kernel_launch(void* const* d_in, const int* in_sizes, int n_in,
                              void* d_out, int out_size, void* d_ws, size_t ws_size,
                              hipStream_t stream)
{
    const float* x  = (const float*)d_in[0];
    const float* e  = (const float*)d_in[1];
    const int*   ei = (const int*)d_in[2];
    const float* bn_node_g = (const float*)d_in[4];
    const float* bn_node_b = (const float*)d_in[5];
    const float* bn_edge_g = (const float*)d_in[6];
    const float* bn_edge_b = (const float*)d_in[7];
    const float* nn1_w1 = (const float*)d_in[8];
    const float* nn1_b1 = (const float*)d_in[9];
    const float* nn1_w2 = (const float*)d_in[10];
    const float* nn1_b2 = (const float*)d_in[11];
    const float* nn2_w1 = (const float*)d_in[12];
    const float* nn2_b1 = (const float*)d_in[13];
    const float* nn2_w2 = (const float*)d_in[14];
    const float* nn2_b2 = (const float*)d_in[15];
    const float* l1_root = (const float*)d_in[16];
    const float* l1_bias = (const float*)d_in[17];
    const float* l2_root = (const float*)d_in[18];
    const float* l2_bias = (const float*)d_in[19];
    const float* mw1 = (const float*)d_in[20]; const float* mb1 = (const float*)d_in[21];
    const float* mw2 = (const float*)d_in[22]; const float* mb2 = (const float*)d_in[23];
    const float* mw3 = (const float*)d_in[24]; const float* mb3 = (const float*)d_in[25];
    const float* mw4 = (const float*)d_in[26]; const float* mb4 = (const float*)d_in[27];
    const float* mw5 = (const float*)d_in[28]; const float* mb5 = (const float*)d_in[29];

    const int* src = ei;
    const int* dst = ei + N_EDGES;

    float* ws = (float*)d_ws;
    float* stats_e = ws;                        // 20 (pad 32)
    float* stats_x = ws + 32;                   // 32
    int* counts = (int*)(ws + 64);              // 20000  (zeroed by memset below)
    int* starts = counts + 20000;               // 20000
    int* cursor = starts + 20000;               // 20000
    int* elist  = cursor + 20000;               // 100000
    float* e_n = ws + 64 + 160000;              // 1,000,000
    float* x_n = e_n + 1000000;                 //   320,000
    float* x1  = x_n + 320000;                  //   640,000
    float* x2  = x1 + 640000;                   // 1,280,000
    float* msg = x2 + 1280000;                  // 6,400,000 (100000*64, shared conv1/conv2)
    unsigned short* h1   = (unsigned short*)(msg + 6400000);   // 100000*32 bf16
    unsigned short* h2   = h1 + 3200000;
    unsigned short* w2t1 = h2 + 3200000;        // 512*32
    unsigned short* w2t2 = w2t1 + 16384;        // 2048*32
    unsigned short* w1t  = w2t2 + 65536;        // 64*160
    float* out = (float*)d_out;

    // zero stats (64 floats) + counts (20000 ints) in one memset
    hipMemsetAsync(d_ws, 0, (64 + 20000) * 4, stream);

    // BN stats + normalize
    stats10_kernel<<<120, 256, 0, stream>>>(e, N_EDGES, stats_e);
    stats16_kernel<<<120, 256, 0, stream>>>(x, N_NODES, stats_x);
    normalize_kernel<10><<<(N_EDGES * 10 + 255) / 256, 256, 0, stream>>>(
        e, N_EDGES, stats_e, bn_edge_g, bn_edge_b, e_n);
    normalize_kernel<16><<<(N_NODES * 16 + 255) / 256, 256, 0, stream>>>(
        x, N_NODES, stats_x, bn_node_g, bn_node_b, x_n);

    // CSR-by-dst (shared by both conv layers — same graph)
    hist_kernel<<<(N_EDGES + 255) / 256, 256, 0, stream>>>(dst, counts, N_EDGES);
    scan_kernel<<<1, 256, 0, stream>>>(counts, starts, cursor, N_NODES);
    scatter_kernel<<<(N_EDGES + 255) / 256, 256, 0, stream>>>(dst, cursor, elist, N_EDGES);

    // weight prep
    w2t_kernel<16, 512><<<2, 256, 0, stream>>>(nn1_w2, w2t1);
    w2t_kernel<32, 2048><<<8, 256, 0, stream>>>(nn2_w2, w2t2);
    w1t_kernel<<<1, 64, 0, stream>>>(mw1, w1t);

    // per-edge hidden vectors for both conv layers
    hgen_both_kernel<<<(N_EDGES + 255) / 256, 256, 0, stream>>>(
        e_n, nn1_w1, nn1_b1, nn2_w1, nn2_b1, h1, h2, N_EDGES);

    const int CONV_BLOCKS = (N_EDGES / 16 + 3) / 4;   // 6250 waves
    const int GATH64 = (N_NODES + 3) / 4;             // 1 node/wave, 4 waves/block
    const int GATH32 = (N_NODES / 2 + 3) / 4;         // 2 nodes/wave

    // layer 1
    root_kernel<16, 32><<<(N_NODES + 255) / 256, 256, 0, stream>>>(x_n, N_NODES, l1_root, l1_bias, x1);
    conv_mfma_kernel<16, 32><<<CONV_BLOCKS, 256, 0, stream>>>(
        h1, w2t1, nn1_b2, src, x_n, msg, N_EDGES);
    gather_kernel<32><<<GATH32, 256, 0, stream>>>(msg, starts, counts, elist, x1, N_NODES);

    // layer 2
    root_kernel<32, 64><<<(N_NODES + 255) / 256, 256, 0, stream>>>(x1, N_NODES, l2_root, l2_bias, x2);
    conv_mfma_kernel<32, 64><<<CONV_BLOCKS, 256, 0, stream>>>(
        h2, w2t2, nn2_b2, src, x1, msg, N_EDGES);
    gather_kernel<64><<<GATH64, 256, 0, stream>>>(msg, starts, counts, elist, x2, N_NODES);

    // edge MLP
    mlp_mfma_kernel<<<(N_EDGES + 63) / 64, 256, 0, stream>>>(
        x2, e_n, src, dst, w1t, mb1, mw2, mb2, mw3, mb3, mw4, mb4, mw5, mb5, out, N_EDGES);
}

// Round 7
// 395.652 us; speedup vs baseline: 3.4043x; 1.1332x over previous
//
#include <hip/hip_runtime.h>
#include <cstdint>

#define N_NODES 20000
#define N_EDGES 100000
#define BN_EPS 1e-5f

typedef __attribute__((ext_vector_type(8))) short short8;
typedef __attribute__((ext_vector_type(4))) float floatx4;

__device__ __forceinline__ float lrelu(float v) { return fmaxf(v, 0.1f * v); }
__device__ __forceinline__ float4 ld4(const float* p) { return *reinterpret_cast<const float4*>(p); }

__device__ __forceinline__ void atomAddF(float* p, float v) {
#if defined(__HIP_DEVICE_COMPILE__)
    unsafeAtomicAdd(p, v);
#else
    atomicAdd(p, v);
#endif
}

// fp32 -> bf16 round-to-nearest-even
__device__ __forceinline__ unsigned short f2bf(float f) {
    union { float f; uint32_t u; } v; v.f = f;
    uint32_t r = v.u + 0x7fffu + ((v.u >> 16) & 1u);
    return (unsigned short)(r >> 16);
}
__device__ __forceinline__ uint32_t pack2(float a, float b) {
    return (uint32_t)f2bf(a) | ((uint32_t)f2bf(b) << 16);
}

// ---------------- column stats, C=10 ----------------
__global__ void stats10_kernel(const float* __restrict__ v, int rows, float* __restrict__ out) {
    __shared__ float sh[20];
    if (threadIdx.x < 20) sh[threadIdx.x] = 0.f;
    __syncthreads();
    int nf2 = rows * 5;
    int stride = gridDim.x * blockDim.x;           // gridDim multiple of 5
    int g = blockIdx.x * blockDim.x + threadIdx.x;
    int c2 = g % 5;
    float s0 = 0.f, s1 = 0.f, q0 = 0.f, q1 = 0.f;
    const float2* p = reinterpret_cast<const float2*>(v);
    for (int i = g; i < nf2; i += stride) {
        float2 t = p[i];
        s0 += t.x; s1 += t.y; q0 += t.x * t.x; q1 += t.y * t.y;
    }
    atomicAdd(&sh[2 * c2], s0);
    atomicAdd(&sh[2 * c2 + 1], s1);
    atomicAdd(&sh[10 + 2 * c2], q0);
    atomicAdd(&sh[10 + 2 * c2 + 1], q1);
    __syncthreads();
    if (threadIdx.x < 20) atomAddF(&out[threadIdx.x], sh[threadIdx.x]);
}

// ---------------- column stats, C=16 ----------------
__global__ void stats16_kernel(const float* __restrict__ v, int rows, float* __restrict__ out) {
    __shared__ float sh[32];
    if (threadIdx.x < 32) sh[threadIdx.x] = 0.f;
    __syncthreads();
    int nf4 = rows * 4;
    int stride = gridDim.x * blockDim.x;
    int g = blockIdx.x * blockDim.x + threadIdx.x;
    int cg = (g & 3) * 4;
    float s[4] = {0.f, 0.f, 0.f, 0.f}, q[4] = {0.f, 0.f, 0.f, 0.f};
    const float4* p = reinterpret_cast<const float4*>(v);
    for (int i = g; i < nf4; i += stride) {
        float4 t = p[i];
        s[0] += t.x; s[1] += t.y; s[2] += t.z; s[3] += t.w;
        q[0] += t.x * t.x; q[1] += t.y * t.y; q[2] += t.z * t.z; q[3] += t.w * t.w;
    }
    #pragma unroll
    for (int off = 32; off >= 4; off >>= 1) {
        #pragma unroll
        for (int j = 0; j < 4; ++j) {
            s[j] += __shfl_down(s[j], off, 64);
            q[j] += __shfl_down(q[j], off, 64);
        }
    }
    if ((threadIdx.x & 63) < 4) {
        #pragma unroll
        for (int j = 0; j < 4; ++j) {
            atomicAdd(&sh[cg + j], s[j]);
            atomicAdd(&sh[16 + cg + j], q[j]);
        }
    }
    __syncthreads();
    if (threadIdx.x < 32) atomAddF(&out[threadIdx.x], sh[threadIdx.x]);
}

// ---------------- batchnorm apply ----------------
template<int C>
__global__ void normalize_kernel(const float* __restrict__ v, int rows,
                                 const float* __restrict__ stats,
                                 const float* __restrict__ g, const float* __restrict__ b,
                                 float* __restrict__ outp) {
    int idx = blockIdx.x * blockDim.x + threadIdx.x;
    int total = rows * C;
    if (idx >= total) return;
    int c = idx % C;
    float N = (float)rows;
    float m = stats[c] / N;
    float var = stats[C + c] / N - m * m;
    float sc = rsqrtf(var + BN_EPS) * g[c];
    outp[idx] = (v[idx] - m) * sc + b[c];
}

// ---------------- CSR-by-dst build ----------------
__global__ void hist_kernel(const int* __restrict__ dst, int* __restrict__ counts, int n) {
    int i = blockIdx.x * blockDim.x + threadIdx.x;
    if (i < n) atomicAdd(&counts[dst[i]], 1);
}

__global__ void scan_kernel(const int* __restrict__ counts, int* __restrict__ starts,
                            int* __restrict__ cursor, int n) {
    __shared__ int part[256];
    const int CH = (n + 255) / 256;
    int t = threadIdx.x;
    int lo = t * CH, hi = min(lo + CH, n);
    int s = 0;
    for (int i = lo; i < hi; ++i) s += counts[i];
    part[t] = s;
    __syncthreads();
    if (t == 0) {
        int acc = 0;
        for (int i = 0; i < 256; ++i) { int v = part[i]; part[i] = acc; acc += v; }
    }
    __syncthreads();
    int acc = part[t];
    for (int i = lo; i < hi; ++i) {
        starts[i] = acc; cursor[i] = acc; acc += counts[i];
    }
}

__global__ void scatter_kernel(const int* __restrict__ dst, int* __restrict__ cursor,
                               int* __restrict__ elist, int n) {
    int i = blockIdx.x * blockDim.x + threadIdx.x;
    if (i < n) {
        int p = atomicAdd(&cursor[dst[i]], 1);
        elist[p] = i;
    }
}

// ---------------- root transform ----------------
template<int CIN, int COUT>
__global__ void root_kernel(const float* __restrict__ xin, int nodes,
                            const float* __restrict__ w, const float* __restrict__ bias,
                            float* __restrict__ xout) {
    int n = blockIdx.x * blockDim.x + threadIdx.x;
    if (n >= nodes) return;
    float xi[CIN];
    #pragma unroll
    for (int i = 0; i < CIN; ++i) xi[i] = xin[n * CIN + i];
    #pragma unroll 4
    for (int o = 0; o < COUT; ++o) {
        float acc = bias[o];
        #pragma unroll
        for (int i = 0; i < CIN; ++i) acc += xi[i] * w[i * COUT + o];
        xout[n * COUT + o] = acc;
    }
}

// ---------------- fused h-gen for BOTH conv layers ----------------
__global__ void hgen_both_kernel(const float* __restrict__ e_n,
                                 const float* __restrict__ w1a, const float* __restrict__ b1a,
                                 const float* __restrict__ w1b, const float* __restrict__ b1b,
                                 unsigned short* __restrict__ h1, unsigned short* __restrict__ h2,
                                 int n_edges)
{
    int e = blockIdx.x * blockDim.x + threadIdx.x;
    if (e >= n_edges) return;
    float ev[10];
    #pragma unroll
    for (int j = 0; j < 10; ++j) ev[j] = e_n[(size_t)e * 10 + j];

    {
        uint32_t pk[16];
        #pragma unroll
        for (int t = 0; t < 16; ++t) pk[t] = 0;
        #pragma unroll
        for (int k = 0; k < 16; k += 2) {
            float a0 = b1a[k], a1 = b1a[k + 1];
            #pragma unroll
            for (int j = 0; j < 10; ++j) {
                a0 += ev[j] * w1a[j * 16 + k];
                a1 += ev[j] * w1a[j * 16 + k + 1];
            }
            pk[k >> 1] = pack2(lrelu(a0), lrelu(a1));
        }
        uint4* o = reinterpret_cast<uint4*>(h1 + (size_t)e * 32);
        o[0] = make_uint4(pk[0], pk[1], pk[2], pk[3]);
        o[1] = make_uint4(pk[4], pk[5], pk[6], pk[7]);
        o[2] = make_uint4(pk[8], pk[9], pk[10], pk[11]);
        o[3] = make_uint4(pk[12], pk[13], pk[14], pk[15]);
    }
    {
        uint32_t pk[16];
        #pragma unroll
        for (int k = 0; k < 32; k += 2) {
            float a0 = b1b[k], a1 = b1b[k + 1];
            #pragma unroll
            for (int j = 0; j < 10; ++j) {
                a0 += ev[j] * w1b[j * 32 + k];
                a1 += ev[j] * w1b[j * 32 + k + 1];
            }
            pk[k >> 1] = pack2(lrelu(a0), lrelu(a1));
        }
        uint4* o = reinterpret_cast<uint4*>(h2 + (size_t)e * 32);
        o[0] = make_uint4(pk[0], pk[1], pk[2], pk[3]);
        o[1] = make_uint4(pk[4], pk[5], pk[6], pk[7]);
        o[2] = make_uint4(pk[8], pk[9], pk[10], pk[11]);
        o[3] = make_uint4(pk[12], pk[13], pk[14], pk[15]);
    }
}

// ---------------- conv weight+bias pack, chunk-major ----------------
// packrow(chunk,i,ol): bf16[32] k-slice of w2[:, i*COUT + chunk*OCH + ol]; per-chunk
// blob = [CIN*OCH rows of 64B | CIN*OCH floats of bias] = 34816 B -> fits static LDS.
template<int CIN, int COUT, int H, int OCH>
__global__ void convpack_kernel(const float* __restrict__ w2, const float* __restrict__ b2,
                                char* __restrict__ pack) {
    constexpr int WB = CIN * OCH * 64;
    constexpr int PACKB = WB + CIN * OCH * 4;
    int r = blockIdx.x * blockDim.x + threadIdx.x;
    if (r >= CIN * COUT) return;
    int chunk = r / (CIN * OCH);
    int rem = r % (CIN * OCH);
    int i = rem / OCH, ol = rem % OCH;
    int n = i * COUT + chunk * OCH + ol;
    char* base = pack + (size_t)chunk * PACKB;
    uint32_t pk[16];
    #pragma unroll
    for (int t = 0; t < 16; ++t) pk[t] = 0;
    #pragma unroll
    for (int k = 0; k < H; k += 2)
        pk[k >> 1] = pack2(w2[(size_t)k * (CIN * COUT) + n],
                           w2[(size_t)(k + 1) * (CIN * COUT) + n]);
    uint4* o = reinterpret_cast<uint4*>((unsigned short*)base + (size_t)rem * 32);
    o[0] = make_uint4(pk[0], pk[1], pk[2], pk[3]);
    o[1] = make_uint4(pk[4], pk[5], pk[6], pk[7]);
    o[2] = make_uint4(pk[8], pk[9], pk[10], pk[11]);
    o[3] = make_uint4(pk[12], pk[13], pk[14], pk[15]);
    ((float*)(base + WB))[rem] = b2[n];
}

__global__ void w1t_kernel(const float* __restrict__ mw1, unsigned short* __restrict__ w1t) {
    int o = blockIdx.x * blockDim.x + threadIdx.x;
    if (o >= 64) return;
    for (int k = 0; k < 160; k += 2) {
        float a = (k < 138) ? mw1[(size_t)k * 64 + o] : 0.f;
        float b = (k + 1 < 138) ? mw1[(size_t)(k + 1) * 64 + o] : 0.f;
        *reinterpret_cast<uint32_t*>(w1t + (size_t)o * 160 + k) = pack2(a, b);
    }
}

// ---------------- NNConv message kernel: LDS-staged weights + MFMA ----------------
// Block = 64 edges x OCH output channels. Stage 34 KB weight/bias chunk in LDS once;
// all A-frags come from ds_read (round-6 version re-streamed 800 MB of w2t from L2
// -> latency-bound at MfmaUtil 5%).
template<int CIN, int COUT, int OCH>
__global__ __launch_bounds__(256, 4)
void conv_lds_kernel(const unsigned short* __restrict__ hbuf,  // [E][32] bf16
                     const char* __restrict__ pack,
                     const int* __restrict__ src,
                     const float* __restrict__ xin,            // [N][CIN]
                     float* __restrict__ msgbuf,               // [E][COUT]
                     int n_edges)
{
    constexpr int NCH = COUT / OCH;
    constexpr int WB = CIN * OCH * 64;
    constexpr int PACKB = WB + CIN * OCH * 4;
    __shared__ char smem[PACKB];

    int tid = threadIdx.x;
    int chunk = blockIdx.x % NCH;          // wave-uniform
    int eblk = blockIdx.x / NCH;

    {   // stage the chunk: 34 KB via uint4 copies
        const uint4* g = reinterpret_cast<const uint4*>(pack + (size_t)chunk * PACKB);
        uint4* s = reinterpret_cast<uint4*>(smem);
        #pragma unroll 1
        for (int o = tid; o < PACKB / 16; o += 256) s[o] = g[o];
    }
    __syncthreads();

    int wv = tid >> 6, lane = tid & 63;
    int el = lane & 15, quad = lane >> 4;
    int e0 = (eblk * 4 + wv) * 16;
    if (e0 >= n_edges) return;             // after the only barrier
    int e = e0 + el;
    int s = src[e];

    const unsigned short* wlds = reinterpret_cast<const unsigned short*>(smem);
    const float* blds = reinterpret_cast<const float*>(smem + WB);

    short8 bfrag = *reinterpret_cast<const short8*>(hbuf + (size_t)e * 32 + quad * 8);

    float xr[CIN];
    #pragma unroll
    for (int i = 0; i < CIN; i += 4) {
        float4 v = ld4(xin + (size_t)s * CIN + i);
        xr[i] = v.x; xr[i + 1] = v.y; xr[i + 2] = v.z; xr[i + 3] = v.w;
    }

    floatx4 msg[OCH / 16];
    #pragma unroll
    for (int t = 0; t < OCH / 16; ++t) msg[t] = (floatx4){0.f, 0.f, 0.f, 0.f};

    #pragma unroll 4
    for (int i = 0; i < CIN; ++i) {
        float xi = xr[i];
        #pragma unroll
        for (int ot = 0; ot < OCH / 16; ++ot) {
            int row = i * OCH + ot * 16 + el;
            short8 af = *reinterpret_cast<const short8*>(wlds + (size_t)row * 32 + quad * 8);
            float4 bb = *reinterpret_cast<const float4*>(blds + i * OCH + ot * 16 + quad * 4);
            floatx4 c = {bb.x, bb.y, bb.z, bb.w};
            c = __builtin_amdgcn_mfma_f32_16x16x32_bf16(af, bfrag, c, 0, 0, 0);
            #pragma unroll
            for (int r = 0; r < 4; ++r)
                msg[ot][r] += xi * lrelu(c[r]);
        }
    }

    float* orow = msgbuf + (size_t)e * COUT + chunk * OCH;
    #pragma unroll
    for (int ot = 0; ot < OCH / 16; ++ot)
        *reinterpret_cast<float4*>(orow + ot * 16 + quad * 4) =
            make_float4(msg[ot][0], msg[ot][1], msg[ot][2], msg[ot][3]);
}

// ---------------- CSR gather ----------------
template<int C>
__global__ __launch_bounds__(256)
void gather_kernel(const float* __restrict__ msg,
                   const int* __restrict__ starts, const int* __restrict__ counts,
                   const int* __restrict__ elist,
                   float* __restrict__ xout, int nodes)
{
    constexpr int NPW = 64 / C;
    int wv = blockIdx.x * 4 + (threadIdx.x >> 6);
    int lane = threadIdx.x & 63;
    int node = wv * NPW + lane / C;
    int ch = lane % C;
    if (node >= nodes) return;
    float acc = xout[(size_t)node * C + ch];
    int s0 = starts[node], cnt = counts[node];
    int i = 0;
    for (; i + 1 < cnt; i += 2) {
        int e0 = elist[s0 + i], e1 = elist[s0 + i + 1];
        float m0 = msg[(size_t)e0 * C + ch];
        float m1 = msg[(size_t)e1 * C + ch];
        acc += m0 + m1;
    }
    if (i < cnt) {
        int e0 = elist[s0 + i];
        acc += msg[(size_t)e0 * C + ch];
    }
    xout[(size_t)node * C + ch] = acc;
}

// ---------------- edge MLP: layer1 MFMA; layers 2-5 split across all 4 waves ----------
__global__ __launch_bounds__(256, 3)
void mlp_mfma_kernel(const float* __restrict__ x2, const float* __restrict__ e_n,
                     const int* __restrict__ src, const int* __restrict__ dst,
                     const unsigned short* __restrict__ w1t, const float* __restrict__ b1,
                     const float* __restrict__ w2, const float* __restrict__ b2,
                     const float* __restrict__ w3, const float* __restrict__ b3,
                     const float* __restrict__ w4, const float* __restrict__ b4,
                     const float* __restrict__ w5, const float* __restrict__ b5,
                     float* __restrict__ out, int n_edges)
{
    __shared__ unsigned short feat[64 * 168];   // 21504 B; reused by a2s/a3s/a4s in phase C
    __shared__ float a1t[4 * 1096];             // per-wave [64 o][16 e], col stride 17

    int tid = threadIdx.x;
    int wv = tid >> 6, lane = tid & 63;
    int el = lane & 15, quad = lane >> 4;
    int eloc = wv * 16 + el;
    int e = blockIdx.x * 64 + eloc;
    int eS = (e < n_edges) ? e : (n_edges - 1);

    // ---- phase A: gather cat(x_src, x_dst, e_attr, 0-pad) -> feat (bf16)
    {
        int row = (quad < 2) ? src[eS] : dst[eS];
        const float* rp = x2 + (size_t)row * 64 + (quad & 1) * 32;
        uint32_t pk[16];
        #pragma unroll
        for (int i = 0; i < 8; ++i) {
            float4 v = ld4(rp + i * 4);
            pk[i * 2]     = pack2(v.x, v.y);
            pk[i * 2 + 1] = pack2(v.z, v.w);
        }
        uint4* fp = reinterpret_cast<uint4*>(&feat[(size_t)eloc * 168 + quad * 32]);
        fp[0] = make_uint4(pk[0], pk[1], pk[2], pk[3]);
        fp[1] = make_uint4(pk[4], pk[5], pk[6], pk[7]);
        fp[2] = make_uint4(pk[8], pk[9], pk[10], pk[11]);
        fp[3] = make_uint4(pk[12], pk[13], pk[14], pk[15]);

        uint32_t t0 = 0, t1 = 0, t2 = 0, t3 = 0;
        if (quad == 0) {
            const float* ep = e_n + (size_t)eS * 10;
            t0 = pack2(ep[0], ep[1]); t1 = pack2(ep[2], ep[3]);
            t2 = pack2(ep[4], ep[5]); t3 = pack2(ep[6], ep[7]);
        } else if (quad == 1) {
            const float* ep = e_n + (size_t)eS * 10;
            t0 = pack2(ep[8], ep[9]);
        }
        uint4* tp = reinterpret_cast<uint4*>(&feat[(size_t)eloc * 168 + 128 + quad * 8]);
        tp[0] = make_uint4(t0, t1, t2, t3);
    }
    __syncthreads();

    // ---- phase B: a1 = lrelu(feat @ w1 + b1) via 20 MFMA -> a1t
    {
        floatx4 acc[4];
        #pragma unroll
        for (int ot = 0; ot < 4; ++ot) {
            float4 bb = ld4(b1 + ot * 16 + quad * 4);
            acc[ot] = (floatx4){bb.x, bb.y, bb.z, bb.w};
        }
        #pragma unroll
        for (int ks = 0; ks < 5; ++ks) {
            short8 bf = *reinterpret_cast<const short8*>(
                &feat[(size_t)eloc * 168 + ks * 32 + quad * 8]);
            #pragma unroll
            for (int ot = 0; ot < 4; ++ot) {
                short8 af = *reinterpret_cast<const short8*>(
                    w1t + (size_t)(ot * 16 + el) * 160 + ks * 32 + quad * 8);
                acc[ot] = __builtin_amdgcn_mfma_f32_16x16x32_bf16(af, bf, acc[ot], 0, 0, 0);
            }
        }
        float* slab = &a1t[wv * 1096];
        #pragma unroll
        for (int ot = 0; ot < 4; ++ot) {
            #pragma unroll
            for (int r = 0; r < 4; ++r)
                slab[(ot * 16 + quad * 4 + r) * 17 + el] = lrelu(acc[ot][r]);
        }
    }
    __syncthreads();

    // ---- phase C: all 256 threads; thread = (edge el2, slice p = wave id)
    float* a2s = reinterpret_cast<float*>(feat);   // [64][33]
    float* a3s = a2s + 64 * 33;                    // [64][17]
    float* a4s = a3s + 64 * 17;                    // [64][9]
    int el2 = tid & 63;
    int p = tid >> 6;                              // wave-uniform -> weights scalarize

    {   // layer 2: 8 outputs per thread
        const float* slab = &a1t[(el2 >> 4) * 1096];
        int col = el2 & 15;
        float a2[8];
        #pragma unroll
        for (int j = 0; j < 8; ++j) a2[j] = b2[p * 8 + j];
        #pragma unroll 4
        for (int i = 0; i < 64; ++i) {
            float ai = slab[i * 17 + col];
            #pragma unroll
            for (int j = 0; j < 8; ++j) a2[j] += ai * w2[i * 32 + p * 8 + j];
        }
        #pragma unroll
        for (int j = 0; j < 8; ++j) a2s[el2 * 33 + p * 8 + j] = lrelu(a2[j]);
    }
    __syncthreads();
    {   // layer 3: 4 outputs per thread
        float a3[4];
        #pragma unroll
        for (int j = 0; j < 4; ++j) a3[j] = b3[p * 4 + j];
        #pragma unroll 4
        for (int i = 0; i < 32; ++i) {
            float ai = a2s[el2 * 33 + i];
            #pragma unroll
            for (int j = 0; j < 4; ++j) a3[j] += ai * w3[i * 16 + p * 4 + j];
        }
        #pragma unroll
        for (int j = 0; j < 4; ++j) a3s[el2 * 17 + p * 4 + j] = lrelu(a3[j]);
    }
    __syncthreads();
    {   // layer 4: 2 outputs per thread
        float a4[2];
        a4[0] = b4[p * 2]; a4[1] = b4[p * 2 + 1];
        #pragma unroll
        for (int i = 0; i < 16; ++i) {
            float ai = a3s[el2 * 17 + i];
            a4[0] += ai * w4[i * 8 + p * 2];
            a4[1] += ai * w4[i * 8 + p * 2 + 1];
        }
        a4s[el2 * 9 + p * 2]     = lrelu(a4[0]);
        a4s[el2 * 9 + p * 2 + 1] = lrelu(a4[1]);
    }
    __syncthreads();
    if (p < 2) {   // layer 5: 2 outputs, one per wave 0/1
        float o = b5[p];
        #pragma unroll
        for (int i = 0; i < 8; ++i) o += a4s[el2 * 9 + i] * w5[i * 2 + p];
        int ce = blockIdx.x * 64 + el2;
        if (ce < n_edges) out[(size_t)ce * 2 + p] = o;
    }
}

// ---------------- launch ----------------
extern "C" void kernel_launch(void* const* d_in, const int* in_sizes, int n_in,
                              void* d_out, int out_size, void* d_ws, size_t ws_size,
                              hipStream_t stream)
{
    const float* x  = (const float*)d_in[0];
    const float* e  = (const float*)d_in[1];
    const int*   ei = (const int*)d_in[2];
    const float* bn_node_g = (const float*)d_in[4];
    const float* bn_node_b = (const float*)d_in[5];
    const float* bn_edge_g = (const float*)d_in[6];
    const float* bn_edge_b = (const float*)d_in[7];
    const float* nn1_w1 = (const float*)d_in[8];
    const float* nn1_b1 = (const float*)d_in[9];
    const float* nn1_w2 = (const float*)d_in[10];
    const float* nn1_b2 = (const float*)d_in[11];
    const float* nn2_w1 = (const float*)d_in[12];
    const float* nn2_b1 = (const float*)d_in[13];
    const float* nn2_w2 = (const float*)d_in[14];
    const float* nn2_b2 = (const float*)d_in[15];
    const float* l1_root = (const float*)d_in[16];
    const float* l1_bias = (const float*)d_in[17];
    const float* l2_root = (const float*)d_in[18];
    const float* l2_bias = (const float*)d_in[19];
    const float* mw1 = (const float*)d_in[20]; const float* mb1 = (const float*)d_in[21];
    const float* mw2 = (const float*)d_in[22]; const float* mb2 = (const float*)d_in[23];
    const float* mw3 = (const float*)d_in[24]; const float* mb3 = (const float*)d_in[25];
    const float* mw4 = (const float*)d_in[26]; const float* mb4 = (const float*)d_in[27];
    const float* mw5 = (const float*)d_in[28]; const float* mb5 = (const float*)d_in[29];

    const int* src = ei;
    const int* dst = ei + N_EDGES;

    float* ws = (float*)d_ws;
    float* stats_e = ws;                        // 20 (pad 32)
    float* stats_x = ws + 32;                   // 32
    int* counts = (int*)(ws + 64);              // 20000  (zeroed by memset)
    int* starts = counts + 20000;               // 20000
    int* cursor = starts + 20000;               // 20000
    int* elist  = cursor + 20000;               // 100000
    float* e_n = ws + 64 + 160000;              // 1,000,000
    float* x_n = e_n + 1000000;                 //   320,000
    float* x1  = x_n + 320000;                  //   640,000
    float* x2  = x1 + 640000;                   // 1,280,000
    float* msg = x2 + 1280000;                  // 6,400,000
    unsigned short* h1   = (unsigned short*)(msg + 6400000);   // 100000*32 bf16
    unsigned short* h2   = h1 + 3200000;
    unsigned short* w1t  = h2 + 3200000;        // 64*160
    char* pack1 = (char*)(w1t + 10240);         // 34816 B
    char* pack2 = pack1 + 34816;                // 4 * 34816 B
    float* out = (float*)d_out;

    hipMemsetAsync(d_ws, 0, (64 + 20000) * 4, stream);

    // BN stats + normalize
    stats10_kernel<<<120, 256, 0, stream>>>(e, N_EDGES, stats_e);
    stats16_kernel<<<120, 256, 0, stream>>>(x, N_NODES, stats_x);
    normalize_kernel<10><<<(N_EDGES * 10 + 255) / 256, 256, 0, stream>>>(
        e, N_EDGES, stats_e, bn_edge_g, bn_edge_b, e_n);
    normalize_kernel<16><<<(N_NODES * 16 + 255) / 256, 256, 0, stream>>>(
        x, N_NODES, stats_x, bn_node_g, bn_node_b, x_n);

    // CSR-by-dst
    hist_kernel<<<(N_EDGES + 255) / 256, 256, 0, stream>>>(dst, counts, N_EDGES);
    scan_kernel<<<1, 256, 0, stream>>>(counts, starts, cursor, N_NODES);
    scatter_kernel<<<(N_EDGES + 255) / 256, 256, 0, stream>>>(dst, cursor, elist, N_EDGES);

    // weight prep
    convpack_kernel<16, 32, 16, 32><<<2, 256, 0, stream>>>(nn1_w2, nn1_b2, pack1);
    convpack_kernel<32, 64, 32, 16><<<8, 256, 0, stream>>>(nn2_w2, nn2_b2, pack2);
    w1t_kernel<<<1, 64, 0, stream>>>(mw1, w1t);

    // per-edge hidden vectors
    hgen_both_kernel<<<(N_EDGES + 255) / 256, 256, 0, stream>>>(
        e_n, nn1_w1, nn1_b1, nn2_w1, nn2_b1, h1, h2, N_EDGES);

    const int EBLK = (N_EDGES + 63) / 64;             // 64 edges per block
    const int GATH64 = (N_NODES + 3) / 4;
    const int GATH32 = (N_NODES / 2 + 3) / 4;

    // layer 1 (OCH = COUT = 32, 1 chunk)
    root_kernel<16, 32><<<(N_NODES + 255) / 256, 256, 0, stream>>>(x_n, N_NODES, l1_root, l1_bias, x1);
    conv_lds_kernel<16, 32, 32><<<EBLK, 256, 0, stream>>>(h1, pack1, src, x_n, msg, N_EDGES);
    gather_kernel<32><<<GATH32, 256, 0, stream>>>(msg, starts, counts, elist, x1, N_NODES);

    // layer 2 (OCH = 16, 4 chunks)
    root_kernel<32, 64><<<(N_NODES + 255) / 256, 256, 0, stream>>>(x1, N_NODES, l2_root, l2_bias, x2);
    conv_lds_kernel<32, 64, 16><<<EBLK * 4, 256, 0, stream>>>(h2, pack2, src, x1, msg, N_EDGES);
    gather_kernel<64><<<GATH64, 256, 0, stream>>>(msg, starts, counts, elist, x2, N_NODES);

    // edge MLP
    mlp_mfma_kernel<<<EBLK, 256, 0, stream>>>(
        x2, e_n, src, dst, w1t, mb1, mw2, mb2, mw3, mb3, mw4, mb4, mw5, mb5, out, N_EDGES);
}

// Round 9
// 341.241 us; speedup vs baseline: 3.9472x; 1.1594x over previous
//
#include <hip/hip_runtime.h>
#include <cstdint>

#define N_NODES 20000
#define N_EDGES 100000
#define BN_EPS 1e-5f

typedef __attribute__((ext_vector_type(8))) short short8;
typedef __attribute__((ext_vector_type(4))) float floatx4;

__device__ __forceinline__ float lrelu(float v) { return fmaxf(v, 0.1f * v); }
__device__ __forceinline__ float4 ld4(const float* p) { return *reinterpret_cast<const float4*>(p); }
__device__ __forceinline__ float2 ld2(const float* p) { return *reinterpret_cast<const float2*>(p); }

__device__ __forceinline__ void atomAddF(float* p, float v) {
#if defined(__HIP_DEVICE_COMPILE__)
    unsafeAtomicAdd(p, v);
#else
    atomicAdd(p, v);
#endif
}

// fp32 -> bf16 round-to-nearest-even
__device__ __forceinline__ unsigned short f2bf(float f) {
    union { float f; uint32_t u; } v; v.f = f;
    uint32_t r = v.u + 0x7fffu + ((v.u >> 16) & 1u);
    return (unsigned short)(r >> 16);
}
__device__ __forceinline__ uint32_t pack2(float a, float b) {
    return (uint32_t)f2bf(a) | ((uint32_t)f2bf(b) << 16);
}
__device__ __forceinline__ short8 pack8(float4 a, float4 b) {
    union { short8 s; uint32_t u[4]; } r;
    r.u[0] = pack2(a.x, a.y); r.u[1] = pack2(a.z, a.w);
    r.u[2] = pack2(b.x, b.y); r.u[3] = pack2(b.z, b.w);
    return r.s;
}

// ================= prep1: stats10 | stats16 | hist | convpack1 | convpack2 | wpack =====
__device__ void stats10_dev(const float* __restrict__ v, int rows, float* __restrict__ out,
                            int blk, int nblk, float* sh) {
    if (threadIdx.x < 20) sh[threadIdx.x] = 0.f;
    __syncthreads();
    int nf2 = rows * 5;
    int stride = nblk * 256;                 // nblk multiple of 5
    int g = blk * 256 + threadIdx.x;
    int c2 = g % 5;
    float s0 = 0.f, s1 = 0.f, q0 = 0.f, q1 = 0.f;
    const float2* p = reinterpret_cast<const float2*>(v);
    for (int i = g; i < nf2; i += stride) {
        float2 t = p[i];
        s0 += t.x; s1 += t.y; q0 += t.x * t.x; q1 += t.y * t.y;
    }
    atomicAdd(&sh[2 * c2], s0);
    atomicAdd(&sh[2 * c2 + 1], s1);
    atomicAdd(&sh[10 + 2 * c2], q0);
    atomicAdd(&sh[10 + 2 * c2 + 1], q1);
    __syncthreads();
    if (threadIdx.x < 20) atomAddF(&out[threadIdx.x], sh[threadIdx.x]);
}

__device__ void stats16_dev(const float* __restrict__ v, int rows, float* __restrict__ out,
                            int blk, int nblk, float* sh) {
    if (threadIdx.x < 32) sh[threadIdx.x] = 0.f;
    __syncthreads();
    int nf4 = rows * 4;
    int stride = nblk * 256;
    int g = blk * 256 + threadIdx.x;
    int cg = (g & 3) * 4;
    float s[4] = {0.f, 0.f, 0.f, 0.f}, q[4] = {0.f, 0.f, 0.f, 0.f};
    const float4* p = reinterpret_cast<const float4*>(v);
    for (int i = g; i < nf4; i += stride) {
        float4 t = p[i];
        s[0] += t.x; s[1] += t.y; s[2] += t.z; s[3] += t.w;
        q[0] += t.x * t.x; q[1] += t.y * t.y; q[2] += t.z * t.z; q[3] += t.w * t.w;
    }
    #pragma unroll
    for (int off = 32; off >= 4; off >>= 1) {
        #pragma unroll
        for (int j = 0; j < 4; ++j) {
            s[j] += __shfl_down(s[j], off, 64);
            q[j] += __shfl_down(q[j], off, 64);
        }
    }
    if ((threadIdx.x & 63) < 4) {
        #pragma unroll
        for (int j = 0; j < 4; ++j) {
            atomicAdd(&sh[cg + j], s[j]);
            atomicAdd(&sh[16 + cg + j], q[j]);
        }
    }
    __syncthreads();
    if (threadIdx.x < 32) atomAddF(&out[threadIdx.x], sh[threadIdx.x]);
}

// pack row r of conv weights: blob per chunk = [CIN*OCH rows x 64B bf16 | CIN*OCH f32 bias]
template<int CIN, int COUT, int H, int OCH>
__device__ void convpack_row(const float* __restrict__ w2, const float* __restrict__ b2,
                             char* __restrict__ pk, int r) {
    constexpr int WB = CIN * OCH * 64;
    constexpr int PACKB = WB + CIN * OCH * 4;
    if (r >= CIN * COUT) return;
    int chunk = r / (CIN * OCH);
    int rem = r % (CIN * OCH);
    int i = rem / OCH, ol = rem % OCH;
    int n = i * COUT + chunk * OCH + ol;
    char* base = pk + (size_t)chunk * PACKB;
    uint32_t pkv[16];
    #pragma unroll
    for (int t = 0; t < 16; ++t) pkv[t] = 0;
    #pragma unroll
    for (int k = 0; k < H; k += 2)
        pkv[k >> 1] = pack2(w2[(size_t)k * (CIN * COUT) + n],
                            w2[(size_t)(k + 1) * (CIN * COUT) + n]);
    uint4* o = reinterpret_cast<uint4*>((unsigned short*)base + (size_t)rem * 32);
    o[0] = make_uint4(pkv[0], pkv[1], pkv[2], pkv[3]);
    o[1] = make_uint4(pkv[4], pkv[5], pkv[6], pkv[7]);
    o[2] = make_uint4(pkv[8], pkv[9], pkv[10], pkv[11]);
    o[3] = make_uint4(pkv[12], pkv[13], pkv[14], pkv[15]);
    ((float*)(base + WB))[rem] = b2[n];
}

#define P1_S10 120
#define P1_S16 120
// blocks: [0,120) s10 | [120,240) s16 | [240,631) hist | [631,633) cp1 | [633,641) cp2 | 641 wpack
__global__ __launch_bounds__(256)
void prep1_kernel(const float* __restrict__ e, const float* __restrict__ x,
                  float* __restrict__ stats_e, float* __restrict__ stats_x,
                  const int* __restrict__ dst, int* __restrict__ counts,
                  const float* __restrict__ nn1_w2, const float* __restrict__ nn1_b2, char* __restrict__ cpack1,
                  const float* __restrict__ nn2_w2, const float* __restrict__ nn2_b2, char* __restrict__ cpack2,
                  const float* __restrict__ mw1, unsigned short* __restrict__ w1t,
                  const float* __restrict__ mw2, const float* __restrict__ mb2,
                  const float* __restrict__ mw3, const float* __restrict__ mb3,
                  const float* __restrict__ mw4, const float* __restrict__ mb4,
                  const float* __restrict__ mw5, const float* __restrict__ mb5,
                  float* __restrict__ mlpw)
{
    __shared__ float sh[32];
    int b = blockIdx.x;
    if (b < P1_S10) {
        stats10_dev(e, N_EDGES, stats_e, b, P1_S10, sh);
    } else if (b < P1_S10 + P1_S16) {
        stats16_dev(x, N_NODES, stats_x, b - P1_S10, P1_S16, sh);
    } else if (b < 631) {
        int i = (b - 240) * 256 + threadIdx.x;
        if (i < N_EDGES) atomicAdd(&counts[dst[i]], 1);
    } else if (b < 633) {
        convpack_row<16, 32, 16, 32>(nn1_w2, nn1_b2, cpack1, (b - 631) * 256 + threadIdx.x);
    } else if (b < 641) {
        convpack_row<32, 64, 32, 16>(nn2_w2, nn2_b2, cpack2, (b - 633) * 256 + threadIdx.x);
    } else {
        // w1t: mw1[138][64] -> [64 rows][160 k] bf16 zero-padded
        if (threadIdx.x < 64) {
            int o = threadIdx.x;
            for (int k = 0; k < 160; k += 2) {
                float a = (k < 138) ? mw1[(size_t)k * 64 + o] : 0.f;
                float c = (k + 1 < 138) ? mw1[(size_t)(k + 1) * 64 + o] : 0.f;
                *reinterpret_cast<uint32_t*>(w1t + (size_t)o * 160 + k) = pack2(a, c);
            }
        }
        // mlpw blob: [w2 2048 | w3 512 | w4 128 | w5 16 | b2 32 | b3 16 | b4 8 | b5 2] (2762, pad 2764)
        for (int i = threadIdx.x; i < 2764; i += 256) {
            float v = 0.f;
            if (i < 2048) v = mw2[i];
            else if (i < 2560) v = mw3[i - 2048];
            else if (i < 2688) v = mw4[i - 2560];
            else if (i < 2704) v = mw5[i - 2688];
            else if (i < 2736) v = mb2[i - 2704];
            else if (i < 2752) v = mb3[i - 2736];
            else if (i < 2760) v = mb4[i - 2752];
            else if (i < 2762) v = mb5[i - 2760];
            mlpw[i] = v;
        }
    }
}

// ================= scan (single block) =================
__global__ void scan_kernel(const int* __restrict__ counts, int* __restrict__ starts,
                            int* __restrict__ cursor, int n) {
    __shared__ int part[256];
    const int CH = (n + 255) / 256;
    int t = threadIdx.x;
    int lo = t * CH, hi = min(lo + CH, n);
    int s = 0;
    for (int i = lo; i < hi; ++i) s += counts[i];
    part[t] = s;
    __syncthreads();
    if (t == 0) {
        int acc = 0;
        for (int i = 0; i < 256; ++i) { int v = part[i]; part[i] = acc; acc += v; }
    }
    __syncthreads();
    int acc = part[t];
    for (int i = lo; i < hi; ++i) {
        starts[i] = acc; cursor[i] = acc; acc += counts[i];
    }
}

// ================= prep2: normalize16 | scatter | hgen(+e-normalize) =================
#define P2_N16 1250
#define P2_SCAT 391
#define P2_HGEN 391
__global__ __launch_bounds__(256)
void prep2_kernel(const float* __restrict__ x, const float* __restrict__ stats_x,
                  const float* __restrict__ bn_node_g, const float* __restrict__ bn_node_b,
                  float* __restrict__ x_n,
                  const int* __restrict__ dst, int* __restrict__ cursor, int* __restrict__ elist,
                  const float* __restrict__ e, const float* __restrict__ stats_e,
                  const float* __restrict__ bn_edge_g, const float* __restrict__ bn_edge_b,
                  float* __restrict__ e_n,
                  const float* __restrict__ w1a, const float* __restrict__ b1a,
                  const float* __restrict__ w1b, const float* __restrict__ b1b,
                  unsigned short* __restrict__ h1, unsigned short* __restrict__ h2)
{
    int b = blockIdx.x;
    if (b < P2_N16) {
        int idx = b * 256 + threadIdx.x;
        if (idx >= N_NODES * 16) return;
        int c = idx & 15;
        float N = (float)N_NODES;
        float m = stats_x[c] / N;
        float var = stats_x[16 + c] / N - m * m;
        float sc = rsqrtf(var + BN_EPS) * bn_node_g[c];
        x_n[idx] = (x[idx] - m) * sc + bn_node_b[c];
    } else if (b < P2_N16 + P2_SCAT) {
        int i = (b - P2_N16) * 256 + threadIdx.x;
        if (i < N_EDGES) {
            int p = atomicAdd(&cursor[dst[i]], 1);
            elist[p] = i;
        }
    } else {
        int eg = (b - P2_N16 - P2_SCAT) * 256 + threadIdx.x;
        if (eg >= N_EDGES) return;
        float ev[10];
        float Ecnt = (float)N_EDGES;
        #pragma unroll
        for (int j = 0; j < 10; ++j) {
            float m = stats_e[j] / Ecnt;
            float var = stats_e[10 + j] / Ecnt - m * m;
            float sc = rsqrtf(var + BN_EPS) * bn_edge_g[j];
            ev[j] = (e[(size_t)eg * 10 + j] - m) * sc + bn_edge_b[j];
            e_n[(size_t)eg * 10 + j] = ev[j];
        }
        {   // h1: H=16 zero-padded to 32
            uint32_t pk[16];
            #pragma unroll
            for (int t = 0; t < 16; ++t) pk[t] = 0;
            #pragma unroll
            for (int k = 0; k < 16; k += 2) {
                float a0 = b1a[k], a1 = b1a[k + 1];
                #pragma unroll
                for (int j = 0; j < 10; ++j) {
                    a0 += ev[j] * w1a[j * 16 + k];
                    a1 += ev[j] * w1a[j * 16 + k + 1];
                }
                pk[k >> 1] = pack2(lrelu(a0), lrelu(a1));
            }
            uint4* o = reinterpret_cast<uint4*>(h1 + (size_t)eg * 32);
            o[0] = make_uint4(pk[0], pk[1], pk[2], pk[3]);
            o[1] = make_uint4(pk[4], pk[5], pk[6], pk[7]);
            o[2] = make_uint4(pk[8], pk[9], pk[10], pk[11]);
            o[3] = make_uint4(pk[12], pk[13], pk[14], pk[15]);
        }
        {   // h2: H=32
            uint32_t pk[16];
            #pragma unroll
            for (int k = 0; k < 32; k += 2) {
                float a0 = b1b[k], a1 = b1b[k + 1];
                #pragma unroll
                for (int j = 0; j < 10; ++j) {
                    a0 += ev[j] * w1b[j * 32 + k];
                    a1 += ev[j] * w1b[j * 32 + k + 1];
                }
                pk[k >> 1] = pack2(lrelu(a0), lrelu(a1));
            }
            uint4* o = reinterpret_cast<uint4*>(h2 + (size_t)eg * 32);
            o[0] = make_uint4(pk[0], pk[1], pk[2], pk[3]);
            o[1] = make_uint4(pk[4], pk[5], pk[6], pk[7]);
            o[2] = make_uint4(pk[8], pk[9], pk[10], pk[11]);
            o[3] = make_uint4(pk[12], pk[13], pk[14], pk[15]);
        }
    }
}

// ================= NNConv message kernel: LDS-staged weights + MFMA =================
template<int CIN, int COUT, int OCH>
__global__ __launch_bounds__(256, 4)
void conv_lds_kernel(const unsigned short* __restrict__ hbuf,
                     const char* __restrict__ pack,
                     const int* __restrict__ src,
                     const float* __restrict__ xin,
                     float* __restrict__ msgbuf,
                     int n_edges)
{
    constexpr int NCH = COUT / OCH;
    constexpr int WB = CIN * OCH * 64;
    constexpr int PACKB = WB + CIN * OCH * 4;
    __shared__ char smem[PACKB];

    int tid = threadIdx.x;
    int chunk = blockIdx.x % NCH;
    int eblk = blockIdx.x / NCH;

    {
        const uint4* g = reinterpret_cast<const uint4*>(pack + (size_t)chunk * PACKB);
        uint4* s = reinterpret_cast<uint4*>(smem);
        #pragma unroll 1
        for (int o = tid; o < PACKB / 16; o += 256) s[o] = g[o];
    }
    __syncthreads();

    int wv = tid >> 6, lane = tid & 63;
    int el = lane & 15, quad = lane >> 4;
    int e0 = (eblk * 4 + wv) * 16;
    if (e0 >= n_edges) return;
    int e = e0 + el;
    int s = src[e];

    const unsigned short* wlds = reinterpret_cast<const unsigned short*>(smem);
    const float* blds = reinterpret_cast<const float*>(smem + WB);

    short8 bfrag = *reinterpret_cast<const short8*>(hbuf + (size_t)e * 32 + quad * 8);

    float xr[CIN];
    #pragma unroll
    for (int i = 0; i < CIN; i += 4) {
        float4 v = ld4(xin + (size_t)s * CIN + i);
        xr[i] = v.x; xr[i + 1] = v.y; xr[i + 2] = v.z; xr[i + 3] = v.w;
    }

    floatx4 msg[OCH / 16];
    #pragma unroll
    for (int t = 0; t < OCH / 16; ++t) msg[t] = (floatx4){0.f, 0.f, 0.f, 0.f};

    #pragma unroll 4
    for (int i = 0; i < CIN; ++i) {
        float xi = xr[i];
        #pragma unroll
        for (int ot = 0; ot < OCH / 16; ++ot) {
            int row = i * OCH + ot * 16 + el;
            short8 af = *reinterpret_cast<const short8*>(wlds + (size_t)row * 32 + quad * 8);
            float4 bb = *reinterpret_cast<const float4*>(blds + i * OCH + ot * 16 + quad * 4);
            floatx4 c = {bb.x, bb.y, bb.z, bb.w};
            c = __builtin_amdgcn_mfma_f32_16x16x32_bf16(af, bfrag, c, 0, 0, 0);
            #pragma unroll
            for (int r = 0; r < 4; ++r)
                msg[ot][r] += xi * lrelu(c[r]);
        }
    }

    float* orow = msgbuf + (size_t)e * COUT + chunk * OCH;
    #pragma unroll
    for (int ot = 0; ot < OCH / 16; ++ot)
        *reinterpret_cast<float4*>(orow + ot * 16 + quad * 4) =
            make_float4(msg[ot][0], msg[ot][1], msg[ot][2], msg[ot][3]);
}

// ================= CSR gather with fused root transform =================
// xout[n][ch] = bias[ch] + sum_i xin[n][i]*w[i][ch] + sum_{e in in(n)} msg[e][ch]
template<int CIN, int C>
__global__ __launch_bounds__(256)
void gather_root_kernel(const float* __restrict__ xin, const float* __restrict__ w,
                        const float* __restrict__ bias,
                        const float* __restrict__ msg,
                        const int* __restrict__ starts, const int* __restrict__ counts,
                        const int* __restrict__ elist,
                        float* __restrict__ xout, int nodes)
{
    constexpr int NPW = 64 / C;
    int wv = blockIdx.x * 4 + (threadIdx.x >> 6);
    int lane = threadIdx.x & 63;
    int node = wv * NPW + lane / C;
    int ch = lane % C;
    if (node >= nodes) return;
    float acc = bias[ch];
    const float* xrow = xin + (size_t)node * CIN;
    #pragma unroll
    for (int i = 0; i < CIN; ++i) acc += xrow[i] * w[i * C + ch];
    int s0 = starts[node], cnt = counts[node];
    int i = 0;
    for (; i + 1 < cnt; i += 2) {
        int e0 = elist[s0 + i], e1 = elist[s0 + i + 1];
        acc += msg[(size_t)e0 * C + ch] + msg[(size_t)e1 * C + ch];
    }
    if (i < cnt) acc += msg[(size_t)elist[s0 + i] * C + ch];
    xout[(size_t)node * C + ch] = acc;
}

// ================= edge MLP v2: wave-synchronous, single barrier =================
// Wave = 16 edges. B-frags built in registers (no feat LDS). Layer1 via 20 MFMA
// (A from w1t, L1-resident). Layers 2-5: lane = (edge=lane&15, slice p=quad),
// weights staged once in LDS, inter-layer scratch wave-local (lockstep => no barrier).
__global__ __launch_bounds__(256)
void mlp2_kernel(const float* __restrict__ x2, const float* __restrict__ e_n,
                 const int* __restrict__ src, const int* __restrict__ dst,
                 const unsigned short* __restrict__ w1t, const float* __restrict__ b1,
                 const float* __restrict__ mlpw,
                 float* __restrict__ out, int n_edges)
{
    __shared__ float wl[2764];        // [w2|w3|w4|w5|b2|b3|b4|b5]
    __shared__ float a1t[4 * 1092];   // per-wave [64 o][16 e], stride 17
    __shared__ float a2scr[4 * 528];  // per-wave [16 e][33]

    int tid = threadIdx.x;
    // stage mlp weights (completes under the barrier below, overlapped with phase A/B)
    {
        const uint4* g = reinterpret_cast<const uint4*>(mlpw);
        uint4* s = reinterpret_cast<uint4*>(wl);
        #pragma unroll 1
        for (int i = tid; i < 691; i += 256) s[i] = g[i];
    }

    int wv = tid >> 6, lane = tid & 63;
    int el = lane & 15, quad = lane >> 4;
    int e = blockIdx.x * 64 + wv * 16 + el;
    int eS = (e < n_edges) ? e : (n_edges - 1);
    int sN = src[eS], dN = dst[eS];

    // ---- build 5 B-frags in registers: feat = [x_src(64) | x_dst(64) | e_n(10) | 0]
    short8 bf[5];
    {
        const float* rs = x2 + (size_t)sN * 64 + quad * 8;
        const float* rd = x2 + (size_t)dN * 64 + quad * 8;
        bf[0] = pack8(ld4(rs), ld4(rs + 4));
        bf[1] = pack8(ld4(rs + 32), ld4(rs + 36));
        bf[2] = pack8(ld4(rd), ld4(rd + 4));
        bf[3] = pack8(ld4(rd + 32), ld4(rd + 36));
        union { short8 s; uint32_t u[4]; } t;
        t.u[0] = t.u[1] = t.u[2] = t.u[3] = 0;
        const float* ep = e_n + (size_t)eS * 10;
        if (quad == 0) {
            float2 p0 = ld2(ep), p1 = ld2(ep + 2), p2 = ld2(ep + 4), p3 = ld2(ep + 6);
            t.u[0] = pack2(p0.x, p0.y); t.u[1] = pack2(p1.x, p1.y);
            t.u[2] = pack2(p2.x, p2.y); t.u[3] = pack2(p3.x, p3.y);
        } else if (quad == 1) {
            float2 p4 = ld2(ep + 8);
            t.u[0] = pack2(p4.x, p4.y);
        }
        bf[4] = t.s;
    }

    // ---- layer 1: 20 MFMA, D col=edge row=o; write transposed to wave slab
    float* slab = &a1t[wv * 1092];
    {
        floatx4 acc[4];
        #pragma unroll
        for (int ot = 0; ot < 4; ++ot) {
            float4 bb = ld4(b1 + ot * 16 + quad * 4);
            acc[ot] = (floatx4){bb.x, bb.y, bb.z, bb.w};
        }
        #pragma unroll
        for (int ks = 0; ks < 5; ++ks) {
            #pragma unroll
            for (int ot = 0; ot < 4; ++ot) {
                short8 af = *reinterpret_cast<const short8*>(
                    w1t + (size_t)(ot * 16 + el) * 160 + ks * 32 + quad * 8);
                acc[ot] = __builtin_amdgcn_mfma_f32_16x16x32_bf16(af, bf[ks], acc[ot], 0, 0, 0);
            }
        }
        #pragma unroll
        for (int ot = 0; ot < 4; ++ot) {
            #pragma unroll
            for (int r = 0; r < 4; ++r)
                slab[(ot * 16 + quad * 4 + r) * 17 + el] = lrelu(acc[ot][r]);
        }
    }
    __syncthreads();   // weight staging visible to all waves

    const float* w2l = wl;            const float* w3l = wl + 2048;
    const float* w4l = wl + 2560;     const float* w5l = wl + 2688;
    const float* b2l = wl + 2704;     const float* b3l = wl + 2736;
    const float* b4l = wl + 2752;     const float* b5l = wl + 2760;
    float* a2s = &a2scr[wv * 528];    // [16 e][33]
    float* a3s = slab;                // alias: a1t slab dead after layer 2 (wave-local)
    float* a4s = slab + 512;
    int p = quad;

    {   // layer 2: 8 outputs per lane
        float a2[8];
        #pragma unroll
        for (int j = 0; j < 8; ++j) a2[j] = b2l[p * 8 + j];
        #pragma unroll 4
        for (int i = 0; i < 64; ++i) {
            float ai = slab[i * 17 + el];
            #pragma unroll
            for (int j = 0; j < 8; ++j) a2[j] += ai * w2l[i * 32 + p * 8 + j];
        }
        #pragma unroll
        for (int j = 0; j < 8; ++j) a2s[el * 33 + p * 8 + j] = lrelu(a2[j]);
    }
    {   // layer 3: 4 outputs per lane
        float a3[4];
        #pragma unroll
        for (int j = 0; j < 4; ++j) a3[j] = b3l[p * 4 + j];
        #pragma unroll 4
        for (int i = 0; i < 32; ++i) {
            float ai = a2s[el * 33 + i];
            #pragma unroll
            for (int j = 0; j < 4; ++j) a3[j] += ai * w3l[i * 16 + p * 4 + j];
        }
        #pragma unroll
        for (int j = 0; j < 4; ++j) a3s[el * 17 + p * 4 + j] = lrelu(a3[j]);
    }
    {   // layer 4: 2 outputs per lane
        float a4[2];
        a4[0] = b4l[p * 2]; a4[1] = b4l[p * 2 + 1];
        #pragma unroll
        for (int i = 0; i < 16; ++i) {
            float ai = a3s[el * 17 + i];
            a4[0] += ai * w4l[i * 8 + p * 2];
            a4[1] += ai * w4l[i * 8 + p * 2 + 1];
        }
        a4s[el * 9 + p * 2]     = lrelu(a4[0]);
        a4s[el * 9 + p * 2 + 1] = lrelu(a4[1]);
    }
    if (p < 2) {   // layer 5
        float o = b5l[p];
        #pragma unroll
        for (int i = 0; i < 8; ++i) o += a4s[el * 9 + i] * w5l[i * 2 + p];
        if (e < n_edges) out[(size_t)e * 2 + p] = o;
    }
}

// ================= launch =================
extern "C" void kernel_launch(void* const* d_in, const int* in_sizes, int n_in,
                              void* d_out, int out_size, void* d_ws, size_t ws_size,
                              hipStream_t stream)
{
    const float* x  = (const float*)d_in[0];
    const float* e  = (const float*)d_in[1];
    const int*   ei = (const int*)d_in[2];
    const float* bn_node_g = (const float*)d_in[4];
    const float* bn_node_b = (const float*)d_in[5];
    const float* bn_edge_g = (const float*)d_in[6];
    const float* bn_edge_b = (const float*)d_in[7];
    const float* nn1_w1 = (const float*)d_in[8];
    const float* nn1_b1 = (const float*)d_in[9];
    const float* nn1_w2 = (const float*)d_in[10];
    const float* nn1_b2 = (const float*)d_in[11];
    const float* nn2_w1 = (const float*)d_in[12];
    const float* nn2_b1 = (const float*)d_in[13];
    const float* nn2_w2 = (const float*)d_in[14];
    const float* nn2_b2 = (const float*)d_in[15];
    const float* l1_root = (const float*)d_in[16];
    const float* l1_bias = (const float*)d_in[17];
    const float* l2_root = (const float*)d_in[18];
    const float* l2_bias = (const float*)d_in[19];
    const float* mw1 = (const float*)d_in[20]; const float* mb1 = (const float*)d_in[21];
    const float* mw2 = (const float*)d_in[22]; const float* mb2 = (const float*)d_in[23];
    const float* mw3 = (const float*)d_in[24]; const float* mb3 = (const float*)d_in[25];
    const float* mw4 = (const float*)d_in[26]; const float* mb4 = (const float*)d_in[27];
    const float* mw5 = (const float*)d_in[28]; const float* mb5 = (const float*)d_in[29];

    const int* src = ei;
    const int* dst = ei + N_EDGES;

    float* ws = (float*)d_ws;
    float* stats_e = ws;                        // 20 (pad 32)
    float* stats_x = ws + 32;                   // 32
    int* counts = (int*)(ws + 64);              // 20000 (zeroed by memset)
    int* starts = counts + 20000;
    int* cursor = starts + 20000;
    int* elist  = cursor + 20000;               // 100000
    float* e_n = ws + 64 + 160000;              // 1,000,000
    float* x_n = e_n + 1000000;                 //   320,000
    float* x1  = x_n + 320000;                  //   640,000
    float* x2  = x1 + 640000;                   // 1,280,000
    float* msg = x2 + 1280000;                  // 6,400,000
    unsigned short* h1   = (unsigned short*)(msg + 6400000);   // 100000*32 bf16
    unsigned short* h2   = h1 + 3200000;
    unsigned short* w1t  = h2 + 3200000;        // 64*160
    char* cpack1 = (char*)(w1t + 10240);        // 34816 B
    char* cpack2 = cpack1 + 34816;              // 4*34816 B
    float* mlpw = (float*)(cpack2 + 4 * 34816); // 2764 floats (16B aligned)
    float* out = (float*)d_out;

    (void)hipMemsetAsync(d_ws, 0, (64 + 20000) * 4, stream);

    prep1_kernel<<<642, 256, 0, stream>>>(
        e, x, stats_e, stats_x, dst, counts,
        nn1_w2, nn1_b2, cpack1, nn2_w2, nn2_b2, cpack2,
        mw1, w1t, mw2, mb2, mw3, mb3, mw4, mb4, mw5, mb5, mlpw);

    scan_kernel<<<1, 256, 0, stream>>>(counts, starts, cursor, N_NODES);

    prep2_kernel<<<P2_N16 + P2_SCAT + P2_HGEN, 256, 0, stream>>>(
        x, stats_x, bn_node_g, bn_node_b, x_n,
        dst, cursor, elist,
        e, stats_e, bn_edge_g, bn_edge_b, e_n,
        nn1_w1, nn1_b1, nn2_w1, nn2_b1, h1, h2);

    const int EBLK = (N_EDGES + 63) / 64;       // 1563

    conv_lds_kernel<16, 32, 32><<<EBLK, 256, 0, stream>>>(h1, cpack1, src, x_n, msg, N_EDGES);
    gather_root_kernel<16, 32><<<(N_NODES / 2 + 3) / 4, 256, 0, stream>>>(
        x_n, l1_root, l1_bias, msg, starts, counts, elist, x1, N_NODES);

    conv_lds_kernel<32, 64, 16><<<EBLK * 4, 256, 0, stream>>>(h2, cpack2, src, x1, msg, N_EDGES);
    gather_root_kernel<32, 64><<<(N_NODES + 3) / 4, 256, 0, stream>>>(
        x1, l2_root, l2_bias, msg, starts, counts, elist, x2, N_NODES);

    mlp2_kernel<<<EBLK, 256, 0, stream>>>(
        x2, e_n, src, dst, w1t, mb1, mlpw, out, N_EDGES);
}